// Round 1
// baseline (4889.662 us; speedup 1.0000x reference)
//
#include <hip/hip_runtime.h>
#include <math.h>

#define BB 2048
#define TT 100
#define DD 128
#define HH 128

__device__ __forceinline__ float sigm(float x) { return 1.f / (1.f + expf(-x)); }

// ---------------- prep: transpose weights ----------------
// WihT/WhhT: (128 x 384)  WihT[k*384+j] = Wih[j*128+k]
// WrT/WuT/WhT: (256 x 128) WrT[k*128+j] = Wr[j*256+k]
// W0T: (512 x 80)  W0T[k*80+j] = attW0[j*512+k]
// W1T: (80 x 40)   W1T[j*40+j2] = attW1[j2*80+j]
__global__ void k_prep(const float* __restrict__ Wih, const float* __restrict__ Whh,
                       const float* __restrict__ Wr, const float* __restrict__ Wu, const float* __restrict__ Wh,
                       const float* __restrict__ attW0, const float* __restrict__ attW1,
                       float* __restrict__ WihT, float* __restrict__ WhhT,
                       float* __restrict__ WrT, float* __restrict__ WuT, float* __restrict__ WhT,
                       float* __restrict__ W0T, float* __restrict__ W1T) {
    int i = blockIdx.x * 256 + threadIdx.x;
    if (i < 384 * 128) { int k = i / 384, j = i - k * 384; WihT[i] = Wih[j * 128 + k]; WhhT[i] = Whh[j * 128 + k]; }
    if (i < 256 * 128) { int k = i / 128, j = i - k * 128; WrT[i] = Wr[j * 256 + k]; WuT[i] = Wu[j * 256 + k]; WhT[i] = Wh[j * 256 + k]; }
    if (i < 512 * 80)  { int k = i / 80,  j = i - k * 80;  W0T[i] = attW0[j * 512 + k]; }
    if (i < 80 * 40)   { int j = i / 40,  j2 = i - j * 40; W1T[i] = attW1[j2 * 80 + j]; }
}

// ---------------- hist_sum ----------------
__global__ void k_hist(const float* __restrict__ hist, const int* __restrict__ len, float* __restrict__ hsum) {
    int b = blockIdx.x, d = threadIdx.x;
    int L = len[b];
    const float* p = hist + (size_t)b * TT * DD + d;
    float s = 0.f;
    for (int t = 0; t < L; ++t) s += p[(size_t)t * DD];
    hsum[b * DD + d] = s / (float)L;
}

// ---------------- GRU scan ----------------
// grid 256 blocks x 768 threads. block handles 8 batch rows for all T steps.
// tid<384: m=0 (x-part, WihT), tid>=384: m=1 (h-part, WhhT); j = column 0..383.
__global__ __launch_bounds__(768) void k_gru(const float* __restrict__ hist,
                                             const float* __restrict__ WihT, const float* __restrict__ WhhT,
                                             const float* __restrict__ bih, const float* __restrict__ bhh,
                                             float* __restrict__ keys) {
    int tid = threadIdx.x;
    int b0 = blockIdx.x * 8;
    int m = tid >= 384;
    int j = m ? tid - 384 : tid;

    __shared__ float4 xs[8][32];
    __shared__ float4 hs[8][32];
    __shared__ float Gi[8][384];
    __shared__ float Gh[8][384];

    for (int e = tid; e < 1024; e += 768) ((float*)hs)[e] = 0.f;
    float bias_j = m ? bhh[j] : bih[j];
    const float* W = m ? WhhT : WihT;
    __syncthreads();

    for (int t = 0; t < TT; ++t) {
        // stage x_t
        for (int e = tid; e < 1024; e += 768) {
            int r = e >> 7, d = e & 127;
            ((float*)xs)[e] = hist[((size_t)(b0 + r) * TT + t) * DD + d];
        }
        __syncthreads();

        const float4(*A)[32] = (const float4(*)[32])(m ? hs : xs);
        float acc[8];
#pragma unroll
        for (int r = 0; r < 8; ++r) acc[r] = bias_j;
#pragma unroll 2
        for (int kc = 0; kc < 32; ++kc) {
            float4 av[8];
#pragma unroll
            for (int r = 0; r < 8; ++r) av[r] = A[r][kc];
            const float* wp = W + kc * 4 * 384 + j;
            float w0 = wp[0], w1 = wp[384], w2 = wp[768], w3 = wp[1152];
#pragma unroll
            for (int r = 0; r < 8; ++r)
                acc[r] += av[r].x * w0 + av[r].y * w1 + av[r].z * w2 + av[r].w * w3;
        }
        float(*Gout)[384] = m ? Gh : Gi;
#pragma unroll
        for (int r = 0; r < 8; ++r) Gout[r][j] = acc[r];
        __syncthreads();

        // gate math over 1024 cells
        for (int e = tid; e < 1024; e += 768) {
            int r = e >> 7, d = e & 127;
            float ir = Gi[r][d], iz = Gi[r][128 + d], inn = Gi[r][256 + d];
            float hr = Gh[r][d], hz = Gh[r][128 + d], hn = Gh[r][256 + d];
            float rr = sigm(ir + hr);
            float zz = sigm(iz + hz);
            float nn = tanhf(inn + rr * hn);
            float hold = ((float*)hs)[e];
            float hnew = (1.f - zz) * nn + zz * hold;
            ((float*)hs)[e] = hnew;
            keys[((size_t)(b0 + r) * TT + t) * HH + d] = hnew;
        }
        __syncthreads();
    }
}

// ---------------- attention MLP (512->80->40->1, all ReLU) ----------------
__global__ void k_attn(const float* __restrict__ keys, const float* __restrict__ item,
                       const float* __restrict__ W0T, const float* __restrict__ b0v,
                       const float* __restrict__ W1T, const float* __restrict__ b1v,
                       const float* __restrict__ W2, const float* __restrict__ b2v,
                       float* __restrict__ scoreRaw) {
    int row = blockIdx.x * 256 + threadIdx.x;
    if (row >= BB * TT) return;
    int b = row / TT;
    const float* kr = keys + (size_t)row * HH;
    const float* qr = item + (size_t)b * DD;

    float acc[80];
#pragma unroll
    for (int j = 0; j < 80; ++j) acc[j] = b0v[j];

    for (int kc = 0; kc < 32; ++kc) {
        float4 kv4 = *(const float4*)(kr + kc * 4);
        float4 qv4 = *(const float4*)(qr + kc * 4);
        float kvs[4] = {kv4.x, kv4.y, kv4.z, kv4.w};
        float qvs[4] = {qv4.x, qv4.y, qv4.z, qv4.w};
#pragma unroll
        for (int i = 0; i < 4; ++i) {
            int k = kc * 4 + i;
            float kv = kvs[i], qv = qvs[i];
            float f2 = kv - qv, f3 = qv * kv;
            const float* w0p = W0T + k * 80;
            const float* w1p = W0T + (128 + k) * 80;
            const float* w2p = W0T + (256 + k) * 80;
            const float* w3p = W0T + (384 + k) * 80;
#pragma unroll
            for (int j = 0; j < 80; ++j)
                acc[j] += kv * w0p[j] + qv * w1p[j] + f2 * w2p[j] + f3 * w3p[j];
        }
    }

    float acc2[40];
#pragma unroll
    for (int j2 = 0; j2 < 40; ++j2) acc2[j2] = b1v[j2];
    for (int j = 0; j < 80; ++j) {
        float av = fmaxf(acc[j], 0.f);
        const float* wp = W1T + j * 40;
#pragma unroll
        for (int j2 = 0; j2 < 40; ++j2) acc2[j2] += av * wp[j2];
    }
    float s = b2v[0];
#pragma unroll
    for (int j2 = 0; j2 < 40; ++j2) s += fmaxf(acc2[j2], 0.f) * W2[j2];
    scoreRaw[row] = fmaxf(s, 0.f);
}

// ---------------- masked softmax + pooled ----------------
__global__ void k_soft(const float* __restrict__ scoreRaw, const int* __restrict__ len,
                       const float* __restrict__ keys, float* __restrict__ pooled) {
    int b = blockIdx.x, tid = threadIdx.x; // 128 threads
    __shared__ float sc[128];
    __shared__ float red[128];
    int L = len[b];
    float s = (tid < L) ? scoreRaw[b * TT + tid] : -INFINITY;
    red[tid] = s;
    __syncthreads();
    for (int o = 64; o > 0; o >>= 1) { if (tid < o) red[tid] = fmaxf(red[tid], red[tid + o]); __syncthreads(); }
    float mx = red[0];
    __syncthreads();
    float e = (tid < L) ? expf(s - mx) : 0.f;
    red[tid] = e;
    __syncthreads();
    for (int o = 64; o > 0; o >>= 1) { if (tid < o) red[tid] += red[tid + o]; __syncthreads(); }
    float inv = 1.f / red[0];
    sc[tid] = e * inv;
    __syncthreads();
    float p = 0.f;
    const float* kb = keys + (size_t)b * TT * HH + tid;
    for (int t2 = 0; t2 < L; ++t2) p += sc[t2] * kb[(size_t)t2 * HH];
    pooled[b * HH + tid] = p;
}

// ---------------- AUGRU scan ----------------
// grid 256 x 768. roles: tid<256 gate r (m=bit7), 256..511 gate u, 512..639 h_hat x-part + phase3.
__global__ __launch_bounds__(768) void k_augru(const float* __restrict__ keys, const float* __restrict__ pooled,
                                               const int* __restrict__ len,
                                               const float* __restrict__ WrT, const float* __restrict__ WuT,
                                               const float* __restrict__ WhT,
                                               const float* __restrict__ br, const float* __restrict__ bu,
                                               const float* __restrict__ bh,
                                               float* __restrict__ att_feat) {
    int tid = threadIdx.x;
    int b0 = blockIdx.x * 8;

    __shared__ float4 xs[8][32];
    __shared__ float4 hs[8][32];
    __shared__ float Grp[2][8][128];
    __shared__ float Gup[2][8][128];
    __shared__ float rh[8][128];
    __shared__ float uu[8][128];
    __shared__ float hh[8][128];
    __shared__ float as_[8];
    __shared__ int ln[8];

    for (int e = tid; e < 1024; e += 768) ((float*)hs)[e] = 0.f;
    if (tid < 8) ln[tid] = len[b0 + tid];
    __syncthreads();

    for (int t = 0; t < TT; ++t) {
        for (int e = tid; e < 1024; e += 768) {
            int r = e >> 7, d = e & 127;
            ((float*)xs)[e] = keys[((size_t)(b0 + r) * TT + t) * HH + d];
        }
        if (tid < 8) as_[tid] = pooled[(b0 + tid) * HH + t];
        __syncthreads();

        float acc[8];
        if (tid < 512) {
            int g = tid >> 8;          // 0 = r gate, 1 = u gate
            int m = (tid >> 7) & 1;    // 0 = h half (W rows 0..127), 1 = x half (rows 128..255)
            int jj = tid & 127;
            const float* W = (g ? WuT : WrT) + (m ? 128 * 128 : 0);
            const float4(*A)[32] = (const float4(*)[32])(m ? xs : hs);
#pragma unroll
            for (int r = 0; r < 8; ++r) acc[r] = 0.f;
#pragma unroll 2
            for (int kc = 0; kc < 32; ++kc) {
                float4 av[8];
#pragma unroll
                for (int r = 0; r < 8; ++r) av[r] = A[r][kc];
                const float* wp = W + kc * 4 * 128 + jj;
                float w0 = wp[0], w1 = wp[128], w2 = wp[256], w3 = wp[384];
#pragma unroll
                for (int r = 0; r < 8; ++r)
                    acc[r] += av[r].x * w0 + av[r].y * w1 + av[r].z * w2 + av[r].w * w3;
            }
            float* Gdst = g ? &Gup[0][0][0] : &Grp[0][0][0];
#pragma unroll
            for (int r = 0; r < 8; ++r) Gdst[(m * 8 + r) * 128 + jj] = acc[r];
        } else if (tid < 640) {
            int jj = tid - 512;        // h_hat x-part (W rows 128..255)
#pragma unroll
            for (int r = 0; r < 8; ++r) acc[r] = 0.f;
#pragma unroll 2
            for (int kc = 0; kc < 32; ++kc) {
                float4 av[8];
#pragma unroll
                for (int r = 0; r < 8; ++r) av[r] = xs[r][kc];
                const float* wp = WhT + (128 + kc * 4) * 128 + jj;
                float w0 = wp[0], w1 = wp[128], w2 = wp[256], w3 = wp[384];
#pragma unroll
                for (int r = 0; r < 8; ++r)
                    acc[r] += av[r].x * w0 + av[r].y * w1 + av[r].z * w2 + av[r].w * w3;
            }
        }
        __syncthreads();

        // phase2: r/u gate nonlinearity, build rh and uu
        for (int e = tid; e < 1024; e += 768) {
            int r = e >> 7, d = e & 127;
            float gr = Grp[0][r][d] + Grp[1][r][d] + br[d];
            float gu = Gup[0][r][d] + Gup[1][r][d] + bu[d];
            float rr = sigm(gr);
            float uv = as_[r] * sigm(gu);
            rh[r][d] = rr * ((float*)hs)[e];
            uu[r][d] = uv;
        }
        __syncthreads();

        // phase3: h_hat h-part (threads 512..639)
        if (tid >= 512 && tid < 640) {
            int jj = tid - 512;
#pragma unroll 2
            for (int kc = 0; kc < 32; ++kc) {
                float4 av[8];
#pragma unroll
                for (int r = 0; r < 8; ++r) av[r] = *(const float4*)&rh[r][kc * 4];
                const float* wp = WhT + kc * 4 * 128 + jj;
                float w0 = wp[0], w1 = wp[128], w2 = wp[256], w3 = wp[384];
#pragma unroll
                for (int r = 0; r < 8; ++r)
                    acc[r] += av[r].x * w0 + av[r].y * w1 + av[r].z * w2 + av[r].w * w3;
            }
#pragma unroll
            for (int r = 0; r < 8; ++r) hh[r][jj] = tanhf(acc[r] + bh[jj]);
        }
        __syncthreads();

        // phase4: h update
        for (int e = tid; e < 1024; e += 768) {
            int r = e >> 7, d = e & 127;
            float hold = ((float*)hs)[e];
            float u = uu[r][d];
            float hnew = (1.f - u) * hold + u * hh[r][d];
            ((float*)hs)[e] = hnew;
            if (t == ln[r] - 1) att_feat[(b0 + r) * HH + d] = hnew;
        }
        __syncthreads();
    }
}

// ---------------- comb build ----------------
__global__ void k_comb(const float* __restrict__ user, const float* __restrict__ item,
                       const float* __restrict__ hsum, const float* __restrict__ attf,
                       float* __restrict__ comb) {
    int gid = blockIdx.x * 256 + threadIdx.x;
    if (gid >= BB * 640) return;
    int b = gid / 640, c = gid - b * 640;
    float v;
    if (c < 128) v = user[b * 128 + c];
    else if (c < 256) v = item[b * 128 + (c - 128)];
    else if (c < 384) v = hsum[b * 128 + (c - 256)];
    else if (c < 512) { int d = c - 384; v = item[b * 128 + d] * hsum[b * 128 + d]; }
    else v = attf[b * 128 + (c - 512)];
    comb[gid] = v;
}

// ---------------- generic sigmoid MLP layer ----------------
__global__ void k_mlp(const float* __restrict__ in, const float* __restrict__ W, const float* __restrict__ bias,
                      float* __restrict__ out, int K, int N) {
    int gid = blockIdx.x * 256 + threadIdx.x;
    if (gid >= BB * N) return;
    int b = gid / N, j = gid - b * N;
    const float* ip = in + (size_t)b * K;
    const float* wp = W + (size_t)j * K;
    float acc = bias[j];
    for (int kc = 0; kc < K / 4; ++kc) {
        float4 x = *(const float4*)(ip + kc * 4);
        float4 w = *(const float4*)(wp + kc * 4);
        acc += x.x * w.x + x.y * w.y + x.z * w.z + x.w * w.w;
    }
    out[(size_t)b * N + j] = sigm(acc);
}

// ---------------- final layer 80->1 ----------------
__global__ void k_final(const float* __restrict__ h2, const float* __restrict__ W, const float* __restrict__ bias,
                        float* __restrict__ out) {
    int b = blockIdx.x * 256 + threadIdx.x;
    if (b >= BB) return;
    const float* ip = h2 + (size_t)b * 80;
    float acc = bias[0];
    for (int k = 0; k < 80; ++k) acc += ip[k] * W[k];
    out[b] = sigm(acc);
}

extern "C" void kernel_launch(void* const* d_in, const int* in_sizes, int n_in,
                              void* d_out, int out_size, void* d_ws, size_t ws_size,
                              hipStream_t stream) {
    const float* user = (const float*)d_in[0];
    const float* hist = (const float*)d_in[1];
    const float* item = (const float*)d_in[2];
    // d_in[3] = mask (unused; equivalent to lengths)
    const int* len = (const int*)d_in[4];
    const float* gWih = (const float*)d_in[5];
    const float* gWhh = (const float*)d_in[6];
    const float* gbih = (const float*)d_in[7];
    const float* gbhh = (const float*)d_in[8];
    const float* aWr = (const float*)d_in[9];
    const float* abr = (const float*)d_in[10];
    const float* aWu = (const float*)d_in[11];
    const float* abu = (const float*)d_in[12];
    const float* aWh = (const float*)d_in[13];
    const float* abh = (const float*)d_in[14];
    const float* attW0 = (const float*)d_in[15];
    const float* attb0 = (const float*)d_in[16];
    const float* attW1 = (const float*)d_in[17];
    const float* attb1 = (const float*)d_in[18];
    const float* attW2 = (const float*)d_in[19];
    const float* attb2 = (const float*)d_in[20];
    const float* phW0 = (const float*)d_in[21];
    const float* phb0 = (const float*)d_in[22];
    const float* phW1 = (const float*)d_in[23];
    const float* phb1 = (const float*)d_in[24];
    const float* phW2 = (const float*)d_in[25];
    const float* phb2 = (const float*)d_in[26];

    char* ws = (char*)d_ws;
    size_t off = 0;
    auto alloc = [&](size_t bytes) { char* p = ws + off; off += (bytes + 255) & ~(size_t)255; return p; };
    float* keys     = (float*)alloc((size_t)BB * TT * HH * 4); // 104.9 MB
    float* scoreRaw = (float*)alloc((size_t)BB * TT * 4);
    float* pooled   = (float*)alloc((size_t)BB * HH * 4);
    float* hsum     = (float*)alloc((size_t)BB * DD * 4);
    float* attf     = (float*)alloc((size_t)BB * HH * 4);
    float* comb     = (float*)alloc((size_t)BB * 640 * 4);
    float* h1       = (float*)alloc((size_t)BB * 200 * 4);
    float* h2       = (float*)alloc((size_t)BB * 80 * 4);
    float* WihT     = (float*)alloc(384 * 128 * 4);
    float* WhhT     = (float*)alloc(384 * 128 * 4);
    float* WrT      = (float*)alloc(256 * 128 * 4);
    float* WuT      = (float*)alloc(256 * 128 * 4);
    float* WhT      = (float*)alloc(256 * 128 * 4);
    float* W0T      = (float*)alloc(512 * 80 * 4);
    float* W1T      = (float*)alloc(80 * 40 * 4);
    (void)ws_size; (void)in_sizes; (void)n_in; (void)out_size;

    k_prep<<<192, 256, 0, stream>>>(gWih, gWhh, aWr, aWu, aWh, attW0, attW1,
                                    WihT, WhhT, WrT, WuT, WhT, W0T, W1T);
    k_hist<<<BB, 128, 0, stream>>>(hist, len, hsum);
    k_gru<<<256, 768, 0, stream>>>(hist, WihT, WhhT, gbih, gbhh, keys);
    k_attn<<<(BB * TT) / 256, 256, 0, stream>>>(keys, item, W0T, attb0, W1T, attb1, attW2, attb2, scoreRaw);
    k_soft<<<BB, 128, 0, stream>>>(scoreRaw, len, keys, pooled);
    k_augru<<<256, 768, 0, stream>>>(keys, pooled, len, WrT, WuT, WhT, abr, abu, abh, attf);
    k_comb<<<(BB * 640) / 256, 256, 0, stream>>>(user, item, hsum, attf, comb);
    k_mlp<<<(BB * 200) / 256, 256, 0, stream>>>(comb, phW0, phb0, h1, 640, 200);
    k_mlp<<<(BB * 80) / 256, 256, 0, stream>>>(h1, phW1, phb1, h2, 200, 80);
    k_final<<<(BB + 255) / 256, 256, 0, stream>>>(h2, phW2, phb2, (float*)d_out);
}

// Round 2
// 3395.490 us; speedup vs baseline: 1.4400x; 1.4400x over previous
//
#include <hip/hip_runtime.h>
#include <math.h>

#define BB 2048
#define TT 100
#define DD 128
#define HH 128

__device__ __forceinline__ float sigm(float x) { return 1.f / (1.f + expf(-x)); }

// ---------------- prep: transpose weights ----------------
__global__ void k_prep(const float* __restrict__ Wih, const float* __restrict__ Whh,
                       const float* __restrict__ Wr, const float* __restrict__ Wu, const float* __restrict__ Wh,
                       const float* __restrict__ attW0, const float* __restrict__ attW1,
                       float* __restrict__ WihT, float* __restrict__ WhhT,
                       float* __restrict__ WrT, float* __restrict__ WuT, float* __restrict__ WhT,
                       float* __restrict__ W0T, float* __restrict__ Wk, float* __restrict__ Wd,
                       float* __restrict__ WqmC, float* __restrict__ W1T) {
    int i = blockIdx.x * 256 + threadIdx.x;
    if (i < 384 * 128) { int k = i / 384, j = i - k * 384; WihT[i] = Wih[j * 128 + k]; WhhT[i] = Whh[j * 128 + k]; }
    if (i < 256 * 128) { int k = i / 128, j = i - k * 128; WrT[i] = Wr[j * 256 + k]; WuT[i] = Wu[j * 256 + k]; WhT[i] = Wh[j * 256 + k]; }
    if (i < 512 * 80)  { int k = i / 80,  j = i - k * 80;  W0T[i] = attW0[j * 512 + k]; }
    if (i < 128 * 80)  { int d = i / 80,  j = i - d * 80;
        Wk[i]   = attW0[j * 512 + d] + attW0[j * 512 + 256 + d];
        Wd[i]   = attW0[j * 512 + 384 + d];
        WqmC[i] = attW0[j * 512 + 128 + d] - attW0[j * 512 + 256 + d]; }
    if (i < 80 * 40)   { int j = i / 40,  j2 = i - j * 40; W1T[i] = attW1[j2 * 80 + j]; }
}

// ---------------- per-b effective layer0 weights ----------------
// Weff[b][d][j] = Wk[d][j] + q_d * Wd[d][j];  bias2[b][j] = b0[j] + sum_d q_d * WqmC[d][j]
__global__ void k_weff(const float* __restrict__ item, const float* __restrict__ Wk, const float* __restrict__ Wd,
                       const float* __restrict__ WqmC, const float* __restrict__ attb0,
                       float* __restrict__ Weff, float* __restrict__ bias2) {
    int b = blockIdx.x, tid = threadIdx.x;
    __shared__ float q[128];
    if (tid < 128) q[tid] = item[b * 128 + tid];
    __syncthreads();
    float* Wb = Weff + (size_t)b * 10240;
    for (int e = tid; e < 10240; e += 256) {
        int d = e / 80;
        Wb[e] = Wk[e] + q[d] * Wd[e];
    }
    if (tid < 80) {
        float s = attb0[tid];
        for (int d = 0; d < 128; ++d) s += q[d] * WqmC[d * 80 + tid];
        bias2[b * 80 + tid] = s;
    }
}

// ---------------- hist_sum ----------------
__global__ void k_hist(const float* __restrict__ hist, const int* __restrict__ len, float* __restrict__ hsum) {
    int b = blockIdx.x, d = threadIdx.x;
    int L = len[b];
    const float* p = hist + (size_t)b * TT * DD + d;
    float s = 0.f;
    for (int t = 0; t < L; ++t) s += p[(size_t)t * DD];
    hsum[b * DD + d] = s / (float)L;
}

// ---------------- GRU scan ----------------
__global__ __launch_bounds__(768) void k_gru(const float* __restrict__ hist,
                                             const float* __restrict__ WihT, const float* __restrict__ WhhT,
                                             const float* __restrict__ bih, const float* __restrict__ bhh,
                                             float* __restrict__ keys) {
    int tid = threadIdx.x;
    int b0 = blockIdx.x * 8;
    int m = tid >= 384;
    int j = m ? tid - 384 : tid;

    __shared__ float4 xs[8][32];
    __shared__ float4 hs[8][32];
    __shared__ float Gi[8][384];
    __shared__ float Gh[8][384];

    for (int e = tid; e < 1024; e += 768) ((float*)hs)[e] = 0.f;
    float bias_j = m ? bhh[j] : bih[j];
    const float* W = m ? WhhT : WihT;
    __syncthreads();

    for (int t = 0; t < TT; ++t) {
        for (int e = tid; e < 1024; e += 768) {
            int r = e >> 7, d = e & 127;
            ((float*)xs)[e] = hist[((size_t)(b0 + r) * TT + t) * DD + d];
        }
        __syncthreads();

        const float4(*A)[32] = (const float4(*)[32])(m ? hs : xs);
        float acc[8];
#pragma unroll
        for (int r = 0; r < 8; ++r) acc[r] = bias_j;
#pragma unroll 2
        for (int kc = 0; kc < 32; ++kc) {
            float4 av[8];
#pragma unroll
            for (int r = 0; r < 8; ++r) av[r] = A[r][kc];
            const float* wp = W + kc * 4 * 384 + j;
            float w0 = wp[0], w1 = wp[384], w2 = wp[768], w3 = wp[1152];
#pragma unroll
            for (int r = 0; r < 8; ++r)
                acc[r] += av[r].x * w0 + av[r].y * w1 + av[r].z * w2 + av[r].w * w3;
        }
        float(*Gout)[384] = m ? Gh : Gi;
#pragma unroll
        for (int r = 0; r < 8; ++r) Gout[r][j] = acc[r];
        __syncthreads();

        for (int e = tid; e < 1024; e += 768) {
            int r = e >> 7, d = e & 127;
            float ir = Gi[r][d], iz = Gi[r][128 + d], inn = Gi[r][256 + d];
            float hr = Gh[r][d], hz = Gh[r][128 + d], hn = Gh[r][256 + d];
            float rr = sigm(ir + hr);
            float zz = sigm(iz + hz);
            float nn = tanhf(inn + rr * hn);
            float hold = ((float*)hs)[e];
            float hnew = (1.f - zz) * nn + zz * hold;
            ((float*)hs)[e] = hnew;
            keys[((size_t)(b0 + r) * TT + t) * HH + d] = hnew;
        }
        __syncthreads();
    }
}

// ---------------- attention MLP, factored layer0 (k @ Weff_b + bias2_b), all ReLU ----------------
__global__ __launch_bounds__(256) void k_attn(const float* __restrict__ keys, const float* __restrict__ Weff,
                                              const float* __restrict__ bias2,
                                              const float* __restrict__ W1T, const float* __restrict__ b1v,
                                              const float* __restrict__ W2, const float* __restrict__ b2v,
                                              float* __restrict__ scoreRaw) {
    int row = blockIdx.x * 256 + threadIdx.x;
    int b = row / TT;
    const float* kr = keys + (size_t)row * HH;
    const float* We = Weff + (size_t)b * 10240;
    const float* bb = bias2 + b * 80;

    float acc[80];
#pragma unroll
    for (int j = 0; j < 80; ++j) acc[j] = bb[j];

    for (int kc = 0; kc < 32; ++kc) {
        float4 k4 = *(const float4*)(kr + kc * 4);
        float ks[4] = {k4.x, k4.y, k4.z, k4.w};
#pragma unroll
        for (int i = 0; i < 4; ++i) {
            const float* wp = We + (kc * 4 + i) * 80;
            float kv = ks[i];
#pragma unroll
            for (int jq = 0; jq < 20; ++jq) {
                float4 w = *(const float4*)(wp + jq * 4);
                acc[jq * 4 + 0] += kv * w.x;
                acc[jq * 4 + 1] += kv * w.y;
                acc[jq * 4 + 2] += kv * w.z;
                acc[jq * 4 + 3] += kv * w.w;
            }
        }
    }

    float acc2[40];
#pragma unroll
    for (int j2 = 0; j2 < 40; ++j2) acc2[j2] = b1v[j2];
#pragma unroll
    for (int j = 0; j < 80; ++j) {
        float av = fmaxf(acc[j], 0.f);
        const float* wp = W1T + j * 40;
#pragma unroll
        for (int q2 = 0; q2 < 10; ++q2) {
            float4 w = *(const float4*)(wp + q2 * 4);
            acc2[q2 * 4 + 0] += av * w.x;
            acc2[q2 * 4 + 1] += av * w.y;
            acc2[q2 * 4 + 2] += av * w.z;
            acc2[q2 * 4 + 3] += av * w.w;
        }
    }
    float s = b2v[0];
#pragma unroll
    for (int j2 = 0; j2 < 40; ++j2) s += fmaxf(acc2[j2], 0.f) * W2[j2];
    scoreRaw[row] = fmaxf(s, 0.f);
}

// ---------------- fallback attention (4-feature, fully unrolled; used if ws too small) ----------------
__global__ __launch_bounds__(256) void k_attn4(const float* __restrict__ keys, const float* __restrict__ item,
                                               const float* __restrict__ W0T, const float* __restrict__ b0v,
                                               const float* __restrict__ W1T, const float* __restrict__ b1v,
                                               const float* __restrict__ W2, const float* __restrict__ b2v,
                                               float* __restrict__ scoreRaw) {
    int row = blockIdx.x * 256 + threadIdx.x;
    if (row >= BB * TT) return;
    int b = row / TT;
    const float* kr = keys + (size_t)row * HH;
    const float* qr = item + (size_t)b * DD;

    float acc[80];
#pragma unroll
    for (int j = 0; j < 80; ++j) acc[j] = b0v[j];

    for (int kc = 0; kc < 32; ++kc) {
        float4 kv4 = *(const float4*)(kr + kc * 4);
        float4 qv4 = *(const float4*)(qr + kc * 4);
        float kvs[4] = {kv4.x, kv4.y, kv4.z, kv4.w};
        float qvs[4] = {qv4.x, qv4.y, qv4.z, qv4.w};
#pragma unroll
        for (int i = 0; i < 4; ++i) {
            int k = kc * 4 + i;
            float kv = kvs[i], qv = qvs[i];
            float f2 = kv - qv, f3 = qv * kv;
            const float* w0p = W0T + k * 80;
            const float* w1p = W0T + (128 + k) * 80;
            const float* w2p = W0T + (256 + k) * 80;
            const float* w3p = W0T + (384 + k) * 80;
#pragma unroll
            for (int j = 0; j < 80; ++j)
                acc[j] += kv * w0p[j] + qv * w1p[j] + f2 * w2p[j] + f3 * w3p[j];
        }
    }

    float acc2[40];
#pragma unroll
    for (int j2 = 0; j2 < 40; ++j2) acc2[j2] = b1v[j2];
#pragma unroll
    for (int j = 0; j < 80; ++j) {
        float av = fmaxf(acc[j], 0.f);
        const float* wp = W1T + j * 40;
#pragma unroll
        for (int j2 = 0; j2 < 40; ++j2) acc2[j2] += av * wp[j2];
    }
    float s = b2v[0];
#pragma unroll
    for (int j2 = 0; j2 < 40; ++j2) s += fmaxf(acc2[j2], 0.f) * W2[j2];
    scoreRaw[row] = fmaxf(s, 0.f);
}

// ---------------- masked softmax + pooled ----------------
__global__ void k_soft(const float* __restrict__ scoreRaw, const int* __restrict__ len,
                       const float* __restrict__ keys, float* __restrict__ pooled) {
    int b = blockIdx.x, tid = threadIdx.x; // 128 threads
    __shared__ float sc[128];
    __shared__ float red[128];
    int L = len[b];
    float s = (tid < L) ? scoreRaw[b * TT + tid] : -INFINITY;
    red[tid] = s;
    __syncthreads();
    for (int o = 64; o > 0; o >>= 1) { if (tid < o) red[tid] = fmaxf(red[tid], red[tid + o]); __syncthreads(); }
    float mx = red[0];
    __syncthreads();
    float e = (tid < L) ? expf(s - mx) : 0.f;
    red[tid] = e;
    __syncthreads();
    for (int o = 64; o > 0; o >>= 1) { if (tid < o) red[tid] += red[tid + o]; __syncthreads(); }
    float inv = 1.f / red[0];
    sc[tid] = e * inv;
    __syncthreads();
    float p = 0.f;
    const float* kb = keys + (size_t)b * TT * HH + tid;
    for (int t2 = 0; t2 < L; ++t2) p += sc[t2] * kb[(size_t)t2 * HH];
    pooled[b * HH + tid] = p;
}

// ---------------- AUGRU scan ----------------
__global__ __launch_bounds__(768) void k_augru(const float* __restrict__ keys, const float* __restrict__ pooled,
                                               const int* __restrict__ len,
                                               const float* __restrict__ WrT, const float* __restrict__ WuT,
                                               const float* __restrict__ WhT,
                                               const float* __restrict__ br, const float* __restrict__ bu,
                                               const float* __restrict__ bh,
                                               float* __restrict__ att_feat) {
    int tid = threadIdx.x;
    int b0 = blockIdx.x * 8;

    __shared__ float4 xs[8][32];
    __shared__ float4 hs[8][32];
    __shared__ float Grp[2][8][128];
    __shared__ float Gup[2][8][128];
    __shared__ float rh[8][128];
    __shared__ float uu[8][128];
    __shared__ float hh[8][128];
    __shared__ float as_[8];
    __shared__ int ln[8];

    for (int e = tid; e < 1024; e += 768) ((float*)hs)[e] = 0.f;
    if (tid < 8) ln[tid] = len[b0 + tid];
    __syncthreads();

    for (int t = 0; t < TT; ++t) {
        for (int e = tid; e < 1024; e += 768) {
            int r = e >> 7, d = e & 127;
            ((float*)xs)[e] = keys[((size_t)(b0 + r) * TT + t) * HH + d];
        }
        if (tid < 8) as_[tid] = pooled[(b0 + tid) * HH + t];
        __syncthreads();

        float acc[8];
        if (tid < 512) {
            int g = tid >> 8;
            int m = (tid >> 7) & 1;
            int jj = tid & 127;
            const float* W = (g ? WuT : WrT) + (m ? 128 * 128 : 0);
            const float4(*A)[32] = (const float4(*)[32])(m ? xs : hs);
#pragma unroll
            for (int r = 0; r < 8; ++r) acc[r] = 0.f;
#pragma unroll 2
            for (int kc = 0; kc < 32; ++kc) {
                float4 av[8];
#pragma unroll
                for (int r = 0; r < 8; ++r) av[r] = A[r][kc];
                const float* wp = W + kc * 4 * 128 + jj;
                float w0 = wp[0], w1 = wp[128], w2 = wp[256], w3 = wp[384];
#pragma unroll
                for (int r = 0; r < 8; ++r)
                    acc[r] += av[r].x * w0 + av[r].y * w1 + av[r].z * w2 + av[r].w * w3;
            }
            float* Gdst = g ? &Gup[0][0][0] : &Grp[0][0][0];
#pragma unroll
            for (int r = 0; r < 8; ++r) Gdst[(m * 8 + r) * 128 + jj] = acc[r];
        } else if (tid < 640) {
            int jj = tid - 512;
#pragma unroll
            for (int r = 0; r < 8; ++r) acc[r] = 0.f;
#pragma unroll 2
            for (int kc = 0; kc < 32; ++kc) {
                float4 av[8];
#pragma unroll
                for (int r = 0; r < 8; ++r) av[r] = xs[r][kc];
                const float* wp = WhT + (128 + kc * 4) * 128 + jj;
                float w0 = wp[0], w1 = wp[128], w2 = wp[256], w3 = wp[384];
#pragma unroll
                for (int r = 0; r < 8; ++r)
                    acc[r] += av[r].x * w0 + av[r].y * w1 + av[r].z * w2 + av[r].w * w3;
            }
        }
        __syncthreads();

        for (int e = tid; e < 1024; e += 768) {
            int r = e >> 7, d = e & 127;
            float gr = Grp[0][r][d] + Grp[1][r][d] + br[d];
            float gu = Gup[0][r][d] + Gup[1][r][d] + bu[d];
            float rr = sigm(gr);
            float uv = as_[r] * sigm(gu);
            rh[r][d] = rr * ((float*)hs)[e];
            uu[r][d] = uv;
        }
        __syncthreads();

        if (tid >= 512 && tid < 640) {
            int jj = tid - 512;
#pragma unroll 2
            for (int kc = 0; kc < 32; ++kc) {
                float4 av[8];
#pragma unroll
                for (int r = 0; r < 8; ++r) av[r] = *(const float4*)&rh[r][kc * 4];
                const float* wp = WhT + kc * 4 * 128 + jj;
                float w0 = wp[0], w1 = wp[128], w2 = wp[256], w3 = wp[384];
#pragma unroll
                for (int r = 0; r < 8; ++r)
                    acc[r] += av[r].x * w0 + av[r].y * w1 + av[r].z * w2 + av[r].w * w3;
            }
#pragma unroll
            for (int r = 0; r < 8; ++r) hh[r][jj] = tanhf(acc[r] + bh[jj]);
        }
        __syncthreads();

        for (int e = tid; e < 1024; e += 768) {
            int r = e >> 7, d = e & 127;
            float hold = ((float*)hs)[e];
            float u = uu[r][d];
            float hnew = (1.f - u) * hold + u * hh[r][d];
            ((float*)hs)[e] = hnew;
            if (t == ln[r] - 1) att_feat[(b0 + r) * HH + d] = hnew;
        }
        __syncthreads();
    }
}

// ---------------- comb build ----------------
__global__ void k_comb(const float* __restrict__ user, const float* __restrict__ item,
                       const float* __restrict__ hsum, const float* __restrict__ attf,
                       float* __restrict__ comb) {
    int gid = blockIdx.x * 256 + threadIdx.x;
    if (gid >= BB * 640) return;
    int b = gid / 640, c = gid - b * 640;
    float v;
    if (c < 128) v = user[b * 128 + c];
    else if (c < 256) v = item[b * 128 + (c - 128)];
    else if (c < 384) v = hsum[b * 128 + (c - 256)];
    else if (c < 512) { int d = c - 384; v = item[b * 128 + d] * hsum[b * 128 + d]; }
    else v = attf[b * 128 + (c - 512)];
    comb[gid] = v;
}

// ---------------- generic sigmoid MLP layer ----------------
__global__ void k_mlp(const float* __restrict__ in, const float* __restrict__ W, const float* __restrict__ bias,
                      float* __restrict__ out, int K, int N) {
    int gid = blockIdx.x * 256 + threadIdx.x;
    if (gid >= BB * N) return;
    int b = gid / N, j = gid - b * N;
    const float* ip = in + (size_t)b * K;
    const float* wp = W + (size_t)j * K;
    float acc = bias[j];
    for (int kc = 0; kc < K / 4; ++kc) {
        float4 x = *(const float4*)(ip + kc * 4);
        float4 w = *(const float4*)(wp + kc * 4);
        acc += x.x * w.x + x.y * w.y + x.z * w.z + x.w * w.w;
    }
    out[(size_t)b * N + j] = sigm(acc);
}

// ---------------- final layer 80->1 ----------------
__global__ void k_final(const float* __restrict__ h2, const float* __restrict__ W, const float* __restrict__ bias,
                        float* __restrict__ out) {
    int b = blockIdx.x * 256 + threadIdx.x;
    if (b >= BB) return;
    const float* ip = h2 + (size_t)b * 80;
    float acc = bias[0];
    for (int k = 0; k < 80; ++k) acc += ip[k] * W[k];
    out[b] = sigm(acc);
}

extern "C" void kernel_launch(void* const* d_in, const int* in_sizes, int n_in,
                              void* d_out, int out_size, void* d_ws, size_t ws_size,
                              hipStream_t stream) {
    const float* user = (const float*)d_in[0];
    const float* hist = (const float*)d_in[1];
    const float* item = (const float*)d_in[2];
    const int* len = (const int*)d_in[4];
    const float* gWih = (const float*)d_in[5];
    const float* gWhh = (const float*)d_in[6];
    const float* gbih = (const float*)d_in[7];
    const float* gbhh = (const float*)d_in[8];
    const float* aWr = (const float*)d_in[9];
    const float* abr = (const float*)d_in[10];
    const float* aWu = (const float*)d_in[11];
    const float* abu = (const float*)d_in[12];
    const float* aWh = (const float*)d_in[13];
    const float* abh = (const float*)d_in[14];
    const float* attW0 = (const float*)d_in[15];
    const float* attb0 = (const float*)d_in[16];
    const float* attW1 = (const float*)d_in[17];
    const float* attb1 = (const float*)d_in[18];
    const float* attW2 = (const float*)d_in[19];
    const float* attb2 = (const float*)d_in[20];
    const float* phW0 = (const float*)d_in[21];
    const float* phb0 = (const float*)d_in[22];
    const float* phW1 = (const float*)d_in[23];
    const float* phb1 = (const float*)d_in[24];
    const float* phW2 = (const float*)d_in[25];
    const float* phb2 = (const float*)d_in[26];

    char* ws = (char*)d_ws;
    size_t off = 0;
    auto alloc = [&](size_t bytes) { char* p = ws + off; off += (bytes + 255) & ~(size_t)255; return p; };
    float* keys     = (float*)alloc((size_t)BB * TT * HH * 4);
    float* scoreRaw = (float*)alloc((size_t)BB * TT * 4);
    float* pooled   = (float*)alloc((size_t)BB * HH * 4);
    float* hsum     = (float*)alloc((size_t)BB * DD * 4);
    float* attf     = (float*)alloc((size_t)BB * HH * 4);
    float* comb     = (float*)alloc((size_t)BB * 640 * 4);
    float* h1       = (float*)alloc((size_t)BB * 200 * 4);
    float* h2       = (float*)alloc((size_t)BB * 80 * 4);
    float* WihT     = (float*)alloc(384 * 128 * 4);
    float* WhhT     = (float*)alloc(384 * 128 * 4);
    float* WrT      = (float*)alloc(256 * 128 * 4);
    float* WuT      = (float*)alloc(256 * 128 * 4);
    float* WhT      = (float*)alloc(256 * 128 * 4);
    float* W0T      = (float*)alloc(512 * 80 * 4);
    float* W1T      = (float*)alloc(80 * 40 * 4);
    float* Wk       = (float*)alloc(128 * 80 * 4);
    float* Wd       = (float*)alloc(128 * 80 * 4);
    float* WqmC     = (float*)alloc(128 * 80 * 4);
    float* bias2    = (float*)alloc((size_t)BB * 80 * 4);
    // large optional buffer LAST so the fallback path never depends on it
    size_t off_base = off;
    float* Weff     = (float*)alloc((size_t)BB * 128 * 80 * 4); // 83.9 MB
    bool useWeff = (off <= ws_size);
    (void)off_base; (void)in_sizes; (void)n_in; (void)out_size;

    k_prep<<<192, 256, 0, stream>>>(gWih, gWhh, aWr, aWu, aWh, attW0, attW1,
                                    WihT, WhhT, WrT, WuT, WhT, W0T, Wk, Wd, WqmC, W1T);
    k_hist<<<BB, 128, 0, stream>>>(hist, len, hsum);
    if (useWeff)
        k_weff<<<BB, 256, 0, stream>>>(item, Wk, Wd, WqmC, attb0, Weff, bias2);
    k_gru<<<256, 768, 0, stream>>>(hist, WihT, WhhT, gbih, gbhh, keys);
    if (useWeff)
        k_attn<<<(BB * TT) / 256, 256, 0, stream>>>(keys, Weff, bias2, W1T, attb1, attW2, attb2, scoreRaw);
    else
        k_attn4<<<(BB * TT) / 256, 256, 0, stream>>>(keys, item, W0T, attb0, W1T, attb1, attW2, attb2, scoreRaw);
    k_soft<<<BB, 128, 0, stream>>>(scoreRaw, len, keys, pooled);
    k_augru<<<256, 768, 0, stream>>>(keys, pooled, len, WrT, WuT, WhT, abr, abu, abh, attf);
    k_comb<<<(BB * 640) / 256, 256, 0, stream>>>(user, item, hsum, attf, comb);
    k_mlp<<<(BB * 200) / 256, 256, 0, stream>>>(comb, phW0, phb0, h1, 640, 200);
    k_mlp<<<(BB * 80) / 256, 256, 0, stream>>>(h1, phW1, phb1, h2, 200, 80);
    k_final<<<(BB + 255) / 256, 256, 0, stream>>>(h2, phW2, phb2, (float*)d_out);
}

// Round 3
// 1125.377 us; speedup vs baseline: 4.3449x; 3.0172x over previous
//
#include <hip/hip_runtime.h>
#include <math.h>

#define BB 2048
#define TT 100
#define DD 128
#define HH 128

typedef __attribute__((ext_vector_type(8))) short bf16x8;
typedef __attribute__((ext_vector_type(4))) float f32x4;

__device__ __forceinline__ float sigm(float x) { return 1.f / (1.f + expf(-x)); }
__device__ __forceinline__ float tanh_fast(float x) {
    x = fminf(fmaxf(x, -15.f), 15.f);
    float e = expf(2.f * x);
    return (e - 1.f) / (e + 1.f);
}
__device__ __forceinline__ short f2bf(float f) {
    union { float f; unsigned u; } v; v.f = f;
    unsigned r = v.u + 0x7FFF + ((v.u >> 16) & 1);
    return (short)(r >> 16);
}

// ---------------- prep: transposes for attention path ----------------
__global__ void k_prep(const float* __restrict__ attW0, const float* __restrict__ attW1,
                       float* __restrict__ W0T, float* __restrict__ Wk, float* __restrict__ Wd,
                       float* __restrict__ WqmC, float* __restrict__ W1T) {
    int i = blockIdx.x * 256 + threadIdx.x;
    if (i < 512 * 80)  { int k = i / 80,  j = i - k * 80;  W0T[i] = attW0[j * 512 + k]; }
    if (i < 128 * 80)  { int d = i / 80,  j = i - d * 80;
        Wk[i]   = attW0[j * 512 + d] + attW0[j * 512 + 256 + d];
        Wd[i]   = attW0[j * 512 + 384 + d];
        WqmC[i] = attW0[j * 512 + 128 + d] - attW0[j * 512 + 256 + d]; }
    if (i < 80 * 40)   { int j = i / 40,  j2 = i - j * 40; W1T[i] = attW1[j2 * 80 + j]; }
}

// ---------------- pack scan weights into MFMA B-fragment order (bf16) ----------------
// Fragment layout (16x16x32): value B[k][n] at lane li, elem e with n=li&15, k=(li>>4)*8+e.
// Flat index: ((tile*NKT + kt)*64 + li)*8 + e, k = kt*32 + (li>>4)*8 + e.
__global__ void k_pack(const float* __restrict__ Wih, const float* __restrict__ Whh,
                       const float* __restrict__ Wr, const float* __restrict__ Wu, const float* __restrict__ Wh,
                       ushort* __restrict__ Pgru, ushort* __restrict__ Pa1, ushort* __restrict__ Pa2) {
    int n = blockIdx.x * 256 + threadIdx.x;
    if (n < 98304) { // GRU: 48 tiles (0..23 -> Wih cols, 24..47 -> Whh cols), 4 k-tiles
        int tile = n >> 11, kt = (n >> 9) & 3, li = (n >> 3) & 63, e = n & 7;
        int k = kt * 32 + (li >> 4) * 8 + e;
        float s;
        if (tile < 24) { int j = tile * 16 + (li & 15); s = Wih[j * 128 + k]; }
        else           { int j = (tile - 24) * 16 + (li & 15); s = Whh[j * 128 + k]; }
        Pgru[n] = (ushort)f2bf(s);
    }
    if (n < 65536) { // AUGRU P1: 16 tiles (cols 0..127 = r via Wr, 128..255 = u via Wu), 8 k-tiles (k<128 h, k>=128 x)
        int tile = n >> 12, kt = (n >> 9) & 7, li = (n >> 3) & 63, e = n & 7;
        int k = kt * 32 + (li >> 4) * 8 + e;
        int jj = tile * 16 + (li & 15);
        float s = (jj < 128) ? Wr[jj * 256 + k] : Wu[(jj - 128) * 256 + k];
        Pa1[n] = (ushort)f2bf(s);
    }
    if (n < 32768) { // AUGRU P2: 8 tiles (Wh cols 0..127), 8 k-tiles
        int tile = n >> 12, kt = (n >> 9) & 7, li = (n >> 3) & 63, e = n & 7;
        int k = kt * 32 + (li >> 4) * 8 + e;
        int j = tile * 16 + (li & 15);
        Pa2[n] = (ushort)f2bf(Wh[j * 256 + k]);
    }
}

// ---------------- per-b effective attention layer0 weights ----------------
__global__ void k_weff(const float* __restrict__ item, const float* __restrict__ Wk, const float* __restrict__ Wd,
                       const float* __restrict__ WqmC, const float* __restrict__ attb0,
                       float* __restrict__ Weff, float* __restrict__ bias2) {
    int b = blockIdx.x, tid = threadIdx.x;
    __shared__ float q[128];
    if (tid < 128) q[tid] = item[b * 128 + tid];
    __syncthreads();
    float* Wb = Weff + (size_t)b * 10240;
    for (int e = tid; e < 10240; e += 256) {
        int d = e / 80;
        Wb[e] = Wk[e] + q[d] * Wd[e];
    }
    if (tid < 80) {
        float s = attb0[tid];
        for (int d = 0; d < 128; ++d) s += q[d] * WqmC[d * 80 + tid];
        bias2[b * 80 + tid] = s;
    }
}

// ---------------- hist_sum ----------------
__global__ void k_hist(const float* __restrict__ hist, const int* __restrict__ len, float* __restrict__ hsum) {
    int b = blockIdx.x, d = threadIdx.x;
    int L = len[b];
    const float* p = hist + (size_t)b * TT * DD + d;
    float s = 0.f;
    for (int t = 0; t < L; ++t) s += p[(size_t)t * DD];
    hsum[b * DD + d] = s / (float)L;
}

// ---------------- GRU scan via MFMA ----------------
// 256 blocks x 512 thr (8 waves). 8 batch rows (M padded to 16).
// Waves 0-3: x-part (Gi, tiles 0..23, A=xbf). Waves 4-7: h-part (Gh, tiles 24..47, A=hbf).
// B-fragments live in VGPRs for all 100 steps.
__global__ __launch_bounds__(512) void k_gru_mfma(const float* __restrict__ hist,
                                                  const ushort* __restrict__ Wp,
                                                  const float* __restrict__ bih, const float* __restrict__ bhh,
                                                  float* __restrict__ keys) {
    int tid = threadIdx.x;
    int lane = tid & 63, w = tid >> 6;
    int b0 = blockIdx.x * 8;

    __shared__ ushort xbf[16 * 128];   // bf16, row-swizzled: byte = row*256 + (off ^ ((row&7)<<4))
    __shared__ ushort hbf[16 * 128];
    __shared__ float  hs[8 * 128];     // f32 h state
    __shared__ float  Glds[48 * 64 * 4]; // C-fragment layout per tile

    for (int e = tid; e < 16 * 128; e += 512) { xbf[e] = 0; hbf[e] = 0; }
    for (int e = tid; e < 8 * 128; e += 512) hs[e] = 0.f;

    bf16x8 bfrag[6][4];
#pragma unroll
    for (int f = 0; f < 6; ++f)
#pragma unroll
        for (int kt = 0; kt < 4; ++kt) {
            int tile = w * 6 + f;
            bfrag[f][kt] = ((const bf16x8*)Wp)[(tile * 4 + kt) * 64 + lane];
        }

    float bi0 = 0, bi1 = 0, bi2 = 0, bq0 = 0, bq1 = 0, bq2 = 0;
    int gd = tid & 127, grq = (tid >> 7) & 1;
    if (tid < 256) {
        bi0 = bih[gd]; bi1 = bih[128 + gd]; bi2 = bih[256 + gd];
        bq0 = bhh[gd]; bq1 = bhh[128 + gd]; bq2 = bhh[256 + gd];
    }
    __syncthreads();

    const ushort* Abuf = (w < 4) ? xbf : hbf;
    int arow = lane & 15, akg = lane >> 4;

    for (int t = 0; t < TT; ++t) {
        // stage x_t -> xbf (rows 0..7)
        {
            int row = tid >> 6, d0 = (tid & 63) * 2;
            float2 v = *(const float2*)&hist[((size_t)(b0 + row) * TT + t) * DD + d0];
            unsigned pv = (unsigned)(unsigned short)f2bf(v.x) | ((unsigned)(unsigned short)f2bf(v.y) << 16);
            *(unsigned*)((char*)xbf + row * 256 + ((d0 * 2) ^ ((row & 7) << 4))) = pv;
        }
        __syncthreads();

        // MFMA phase: 6 col-tiles x 4 k-tiles per wave
        {
            bf16x8 af[4];
#pragma unroll
            for (int kt = 0; kt < 4; ++kt) {
                int byte = (kt * 64 + akg * 16) ^ ((arow & 7) << 4);
                af[kt] = *(const bf16x8*)((const char*)Abuf + arow * 256 + byte);
            }
#pragma unroll
            for (int f = 0; f < 6; ++f) {
                f32x4 acc = {0.f, 0.f, 0.f, 0.f};
#pragma unroll
                for (int kt = 0; kt < 4; ++kt)
                    acc = __builtin_amdgcn_mfma_f32_16x16x32_bf16(af[kt], bfrag[f][kt], acc, 0, 0, 0);
                int tile = w * 6 + f;
                *(f32x4*)&Glds[(tile * 64 + lane) * 4] = acc;
            }
        }
        __syncthreads();

        // gate phase: 256 threads, each (rq, d) covers rows rq*4..rq*4+3
        if (tid < 256) {
            int d = gd, rq = grq;
            int ti = d >> 4, lidx = rq * 16 + (d & 15);
            f32x4 gi0 = *(const f32x4*)&Glds[((ti) * 64 + lidx) * 4];
            f32x4 gi1 = *(const f32x4*)&Glds[((8 + ti) * 64 + lidx) * 4];
            f32x4 gi2 = *(const f32x4*)&Glds[((16 + ti) * 64 + lidx) * 4];
            f32x4 gh0 = *(const f32x4*)&Glds[((24 + ti) * 64 + lidx) * 4];
            f32x4 gh1 = *(const f32x4*)&Glds[((32 + ti) * 64 + lidx) * 4];
            f32x4 gh2 = *(const f32x4*)&Glds[((40 + ti) * 64 + lidx) * 4];
#pragma unroll
            for (int i = 0; i < 4; ++i) {
                int row = rq * 4 + i;
                float ir = gi0[i] + bi0, iz = gi1[i] + bi1, in_ = gi2[i] + bi2;
                float hr = gh0[i] + bq0, hz = gh1[i] + bq1, hn = gh2[i] + bq2;
                float r = sigm(ir + hr);
                float z = sigm(iz + hz);
                float nn = tanh_fast(in_ + r * hn);
                float hold = hs[row * 128 + d];
                float hnew = (1.f - z) * nn + z * hold;
                hs[row * 128 + d] = hnew;
                *(short*)((char*)hbf + row * 256 + ((d * 2) ^ ((row & 7) << 4))) = f2bf(hnew);
                keys[((size_t)(b0 + row) * TT + t) * HH + d] = hnew;
            }
        }
        __syncthreads();
    }
}

// ---------------- AUGRU scan via MFMA ----------------
// P1: [h|x](K=256) @ [Wr|Wu cols](N=256): 16 tiles, wave w -> tiles {2w,2w+1}.
// P2: [h*r|x](K=256) @ Wh (N=128): 8 tiles, wave w -> tile w.
__global__ __launch_bounds__(512) void k_augru_mfma(const float* __restrict__ keys,
                                                    const float* __restrict__ pooled,
                                                    const int* __restrict__ len,
                                                    const ushort* __restrict__ Wp1, const ushort* __restrict__ Wp2,
                                                    const float* __restrict__ br, const float* __restrict__ bu,
                                                    const float* __restrict__ bh,
                                                    float* __restrict__ att_feat) {
    int tid = threadIdx.x;
    int lane = tid & 63, w = tid >> 6;
    int b0 = blockIdx.x * 8;

    __shared__ ushort hbf[16 * 128], xbf[16 * 128], rhbf[16 * 128];
    __shared__ float hs[8 * 128];
    __shared__ float G1[16 * 64 * 4], G2[8 * 64 * 4];
    __shared__ float as_[8];
    __shared__ int ln[8];

    for (int e = tid; e < 16 * 128; e += 512) { hbf[e] = 0; xbf[e] = 0; rhbf[e] = 0; }
    for (int e = tid; e < 8 * 128; e += 512) hs[e] = 0.f;
    if (tid < 8) ln[tid] = len[b0 + tid];

    bf16x8 b1frag[2][8];
    bf16x8 b2frag[8];
#pragma unroll
    for (int f = 0; f < 2; ++f)
#pragma unroll
        for (int kt = 0; kt < 8; ++kt)
            b1frag[f][kt] = ((const bf16x8*)Wp1)[((w * 2 + f) * 8 + kt) * 64 + lane];
#pragma unroll
    for (int kt = 0; kt < 8; ++kt)
        b2frag[kt] = ((const bf16x8*)Wp2)[(w * 8 + kt) * 64 + lane];

    float brr = 0, buu = 0, bhh_ = 0;
    int gd = tid & 127, grq = (tid >> 7) & 1;
    if (tid < 256) { brr = br[gd]; buu = bu[gd]; bhh_ = bh[gd]; }
    __syncthreads();

    int arow = lane & 15, akg = lane >> 4;

    for (int t = 0; t < TT; ++t) {
        // stage x_t = keys[:, t] -> xbf; a_t
        {
            int row = tid >> 6, d0 = (tid & 63) * 2;
            float2 v = *(const float2*)&keys[((size_t)(b0 + row) * TT + t) * HH + d0];
            unsigned pv = (unsigned)(unsigned short)f2bf(v.x) | ((unsigned)(unsigned short)f2bf(v.y) << 16);
            *(unsigned*)((char*)xbf + row * 256 + ((d0 * 2) ^ ((row & 7) << 4))) = pv;
        }
        if (tid < 8) as_[tid] = pooled[(b0 + tid) * HH + t];
        __syncthreads();

        // P1 MFMA
        {
            bf16x8 af[8];
#pragma unroll
            for (int kt = 0; kt < 8; ++kt) {
                const ushort* buf = (kt < 4) ? hbf : xbf;
                int kk = kt & 3;
                int byte = (kk * 64 + akg * 16) ^ ((arow & 7) << 4);
                af[kt] = *(const bf16x8*)((const char*)buf + arow * 256 + byte);
            }
#pragma unroll
            for (int f = 0; f < 2; ++f) {
                f32x4 acc = {0.f, 0.f, 0.f, 0.f};
#pragma unroll
                for (int kt = 0; kt < 8; ++kt)
                    acc = __builtin_amdgcn_mfma_f32_16x16x32_bf16(af[kt], b1frag[f][kt], acc, 0, 0, 0);
                *(f32x4*)&G1[((w * 2 + f) * 64 + lane) * 4] = acc;
            }
        }
        __syncthreads();

        float u_reg[4], hold_reg[4];
        // gate1: r, u; write rh (bf16) for P2
        if (tid < 256) {
            int d = gd, rq = grq;
            int ti = d >> 4, lidx = rq * 16 + (d & 15);
            f32x4 gr = *(const f32x4*)&G1[((ti) * 64 + lidx) * 4];
            f32x4 gu = *(const f32x4*)&G1[((8 + ti) * 64 + lidx) * 4];
#pragma unroll
            for (int i = 0; i < 4; ++i) {
                int row = rq * 4 + i;
                float r = sigm(gr[i] + brr);
                float u = as_[row] * sigm(gu[i] + buu);
                float hold = hs[row * 128 + d];
                u_reg[i] = u; hold_reg[i] = hold;
                *(short*)((char*)rhbf + row * 256 + ((d * 2) ^ ((row & 7) << 4))) = f2bf(r * hold);
            }
        }
        __syncthreads();

        // P2 MFMA
        {
            bf16x8 af[8];
#pragma unroll
            for (int kt = 0; kt < 8; ++kt) {
                const ushort* buf = (kt < 4) ? rhbf : xbf;
                int kk = kt & 3;
                int byte = (kk * 64 + akg * 16) ^ ((arow & 7) << 4);
                af[kt] = *(const bf16x8*)((const char*)buf + arow * 256 + byte);
            }
            f32x4 acc = {0.f, 0.f, 0.f, 0.f};
#pragma unroll
            for (int kt = 0; kt < 8; ++kt)
                acc = __builtin_amdgcn_mfma_f32_16x16x32_bf16(af[kt], b2frag[kt], acc, 0, 0, 0);
            *(f32x4*)&G2[(w * 64 + lane) * 4] = acc;
        }
        __syncthreads();

        // gate2: h update
        if (tid < 256) {
            int d = gd, rq = grq;
            int ti = d >> 4, lidx = rq * 16 + (d & 15);
            f32x4 g2 = *(const f32x4*)&G2[(ti * 64 + lidx) * 4];
#pragma unroll
            for (int i = 0; i < 4; ++i) {
                int row = rq * 4 + i;
                float hhat = tanh_fast(g2[i] + bhh_);
                float u = u_reg[i];
                float hnew = (1.f - u) * hold_reg[i] + u * hhat;
                hs[row * 128 + d] = hnew;
                *(short*)((char*)hbf + row * 256 + ((d * 2) ^ ((row & 7) << 4))) = f2bf(hnew);
                if (t == ln[row] - 1) att_feat[(b0 + row) * HH + d] = hnew;
            }
        }
        __syncthreads();
    }
}

// ---------------- attention MLP, factored layer0 ----------------
__global__ __launch_bounds__(256) void k_attn(const float* __restrict__ keys, const float* __restrict__ Weff,
                                              const float* __restrict__ bias2,
                                              const float* __restrict__ W1T, const float* __restrict__ b1v,
                                              const float* __restrict__ W2, const float* __restrict__ b2v,
                                              float* __restrict__ scoreRaw) {
    int row = blockIdx.x * 256 + threadIdx.x;
    int b = row / TT;
    const float* kr = keys + (size_t)row * HH;
    const float* We = Weff + (size_t)b * 10240;
    const float* bb = bias2 + b * 80;

    float acc[80];
#pragma unroll
    for (int j = 0; j < 80; ++j) acc[j] = bb[j];

    for (int kc = 0; kc < 32; ++kc) {
        float4 k4 = *(const float4*)(kr + kc * 4);
        float ks[4] = {k4.x, k4.y, k4.z, k4.w};
#pragma unroll
        for (int i = 0; i < 4; ++i) {
            const float* wp = We + (kc * 4 + i) * 80;
            float kv = ks[i];
#pragma unroll
            for (int jq = 0; jq < 20; ++jq) {
                float4 w = *(const float4*)(wp + jq * 4);
                acc[jq * 4 + 0] += kv * w.x;
                acc[jq * 4 + 1] += kv * w.y;
                acc[jq * 4 + 2] += kv * w.z;
                acc[jq * 4 + 3] += kv * w.w;
            }
        }
    }

    float acc2[40];
#pragma unroll
    for (int j2 = 0; j2 < 40; ++j2) acc2[j2] = b1v[j2];
#pragma unroll
    for (int j = 0; j < 80; ++j) {
        float av = fmaxf(acc[j], 0.f);
        const float* wp = W1T + j * 40;
#pragma unroll
        for (int q2 = 0; q2 < 10; ++q2) {
            float4 w = *(const float4*)(wp + q2 * 4);
            acc2[q2 * 4 + 0] += av * w.x;
            acc2[q2 * 4 + 1] += av * w.y;
            acc2[q2 * 4 + 2] += av * w.z;
            acc2[q2 * 4 + 3] += av * w.w;
        }
    }
    float s = b2v[0];
#pragma unroll
    for (int j2 = 0; j2 < 40; ++j2) s += fmaxf(acc2[j2], 0.f) * W2[j2];
    scoreRaw[row] = fmaxf(s, 0.f);
}

// ---------------- fallback attention (4-feature, fully unrolled) ----------------
__global__ __launch_bounds__(256) void k_attn4(const float* __restrict__ keys, const float* __restrict__ item,
                                               const float* __restrict__ W0T, const float* __restrict__ b0v,
                                               const float* __restrict__ W1T, const float* __restrict__ b1v,
                                               const float* __restrict__ W2, const float* __restrict__ b2v,
                                               float* __restrict__ scoreRaw) {
    int row = blockIdx.x * 256 + threadIdx.x;
    if (row >= BB * TT) return;
    int b = row / TT;
    const float* kr = keys + (size_t)row * HH;
    const float* qr = item + (size_t)b * DD;

    float acc[80];
#pragma unroll
    for (int j = 0; j < 80; ++j) acc[j] = b0v[j];

    for (int kc = 0; kc < 32; ++kc) {
        float4 kv4 = *(const float4*)(kr + kc * 4);
        float4 qv4 = *(const float4*)(qr + kc * 4);
        float kvs[4] = {kv4.x, kv4.y, kv4.z, kv4.w};
        float qvs[4] = {qv4.x, qv4.y, qv4.z, qv4.w};
#pragma unroll
        for (int i = 0; i < 4; ++i) {
            int k = kc * 4 + i;
            float kv = kvs[i], qv = qvs[i];
            float f2 = kv - qv, f3 = qv * kv;
            const float* w0p = W0T + k * 80;
            const float* w1p = W0T + (128 + k) * 80;
            const float* w2p = W0T + (256 + k) * 80;
            const float* w3p = W0T + (384 + k) * 80;
#pragma unroll
            for (int j = 0; j < 80; ++j)
                acc[j] += kv * w0p[j] + qv * w1p[j] + f2 * w2p[j] + f3 * w3p[j];
        }
    }

    float acc2[40];
#pragma unroll
    for (int j2 = 0; j2 < 40; ++j2) acc2[j2] = b1v[j2];
#pragma unroll
    for (int j = 0; j < 80; ++j) {
        float av = fmaxf(acc[j], 0.f);
        const float* wp = W1T + j * 40;
#pragma unroll
        for (int j2 = 0; j2 < 40; ++j2) acc2[j2] += av * wp[j2];
    }
    float s = b2v[0];
#pragma unroll
    for (int j2 = 0; j2 < 40; ++j2) s += fmaxf(acc2[j2], 0.f) * W2[j2];
    scoreRaw[row] = fmaxf(s, 0.f);
}

// ---------------- masked softmax + pooled ----------------
__global__ void k_soft(const float* __restrict__ scoreRaw, const int* __restrict__ len,
                       const float* __restrict__ keys, float* __restrict__ pooled) {
    int b = blockIdx.x, tid = threadIdx.x; // 128 threads
    __shared__ float sc[128];
    __shared__ float red[128];
    int L = len[b];
    float s = (tid < L) ? scoreRaw[b * TT + tid] : -INFINITY;
    red[tid] = s;
    __syncthreads();
    for (int o = 64; o > 0; o >>= 1) { if (tid < o) red[tid] = fmaxf(red[tid], red[tid + o]); __syncthreads(); }
    float mx = red[0];
    __syncthreads();
    float e = (tid < L) ? expf(s - mx) : 0.f;
    red[tid] = e;
    __syncthreads();
    for (int o = 64; o > 0; o >>= 1) { if (tid < o) red[tid] += red[tid + o]; __syncthreads(); }
    float inv = 1.f / red[0];
    sc[tid] = e * inv;
    __syncthreads();
    float p = 0.f;
    const float* kb = keys + (size_t)b * TT * HH + tid;
    for (int t2 = 0; t2 < L; ++t2) p += sc[t2] * kb[(size_t)t2 * HH];
    pooled[b * HH + tid] = p;
}

// ---------------- comb build ----------------
__global__ void k_comb(const float* __restrict__ user, const float* __restrict__ item,
                       const float* __restrict__ hsum, const float* __restrict__ attf,
                       float* __restrict__ comb) {
    int gid = blockIdx.x * 256 + threadIdx.x;
    if (gid >= BB * 640) return;
    int b = gid / 640, c = gid - b * 640;
    float v;
    if (c < 128) v = user[b * 128 + c];
    else if (c < 256) v = item[b * 128 + (c - 128)];
    else if (c < 384) v = hsum[b * 128 + (c - 256)];
    else if (c < 512) { int d = c - 384; v = item[b * 128 + d] * hsum[b * 128 + d]; }
    else v = attf[b * 128 + (c - 512)];
    comb[gid] = v;
}

// ---------------- generic sigmoid MLP layer ----------------
__global__ void k_mlp(const float* __restrict__ in, const float* __restrict__ W, const float* __restrict__ bias,
                      float* __restrict__ out, int K, int N) {
    int gid = blockIdx.x * 256 + threadIdx.x;
    if (gid >= BB * N) return;
    int b = gid / N, j = gid - b * N;
    const float* ip = in + (size_t)b * K;
    const float* wp = W + (size_t)j * K;
    float acc = bias[j];
    for (int kc = 0; kc < K / 4; ++kc) {
        float4 x = *(const float4*)(ip + kc * 4);
        float4 w = *(const float4*)(wp + kc * 4);
        acc += x.x * w.x + x.y * w.y + x.z * w.z + x.w * w.w;
    }
    out[(size_t)b * N + j] = sigm(acc);
}

// ---------------- final layer 80->1 ----------------
__global__ void k_final(const float* __restrict__ h2, const float* __restrict__ W, const float* __restrict__ bias,
                        float* __restrict__ out) {
    int b = blockIdx.x * 256 + threadIdx.x;
    if (b >= BB) return;
    const float* ip = h2 + (size_t)b * 80;
    float acc = bias[0];
    for (int k = 0; k < 80; ++k) acc += ip[k] * W[k];
    out[b] = sigm(acc);
}

extern "C" void kernel_launch(void* const* d_in, const int* in_sizes, int n_in,
                              void* d_out, int out_size, void* d_ws, size_t ws_size,
                              hipStream_t stream) {
    const float* user = (const float*)d_in[0];
    const float* hist = (const float*)d_in[1];
    const float* item = (const float*)d_in[2];
    const int* len = (const int*)d_in[4];
    const float* gWih = (const float*)d_in[5];
    const float* gWhh = (const float*)d_in[6];
    const float* gbih = (const float*)d_in[7];
    const float* gbhh = (const float*)d_in[8];
    const float* aWr = (const float*)d_in[9];
    const float* abr = (const float*)d_in[10];
    const float* aWu = (const float*)d_in[11];
    const float* abu = (const float*)d_in[12];
    const float* aWh = (const float*)d_in[13];
    const float* abh = (const float*)d_in[14];
    const float* attW0 = (const float*)d_in[15];
    const float* attb0 = (const float*)d_in[16];
    const float* attW1 = (const float*)d_in[17];
    const float* attb1 = (const float*)d_in[18];
    const float* attW2 = (const float*)d_in[19];
    const float* attb2 = (const float*)d_in[20];
    const float* phW0 = (const float*)d_in[21];
    const float* phb0 = (const float*)d_in[22];
    const float* phW1 = (const float*)d_in[23];
    const float* phb1 = (const float*)d_in[24];
    const float* phW2 = (const float*)d_in[25];
    const float* phb2 = (const float*)d_in[26];

    char* ws = (char*)d_ws;
    size_t off = 0;
    auto alloc = [&](size_t bytes) { char* p = ws + off; off += (bytes + 255) & ~(size_t)255; return p; };
    float* keys     = (float*)alloc((size_t)BB * TT * HH * 4);
    float* scoreRaw = (float*)alloc((size_t)BB * TT * 4);
    float* pooled   = (float*)alloc((size_t)BB * HH * 4);
    float* hsum     = (float*)alloc((size_t)BB * DD * 4);
    float* attf     = (float*)alloc((size_t)BB * HH * 4);
    float* comb     = (float*)alloc((size_t)BB * 640 * 4);
    float* h1       = (float*)alloc((size_t)BB * 200 * 4);
    float* h2       = (float*)alloc((size_t)BB * 80 * 4);
    float* W0T      = (float*)alloc(512 * 80 * 4);
    float* W1T      = (float*)alloc(80 * 40 * 4);
    float* Wk       = (float*)alloc(128 * 80 * 4);
    float* Wd       = (float*)alloc(128 * 80 * 4);
    float* WqmC     = (float*)alloc(128 * 80 * 4);
    float* bias2    = (float*)alloc((size_t)BB * 80 * 4);
    ushort* Pgru    = (ushort*)alloc(98304 * 2);
    ushort* Pa1     = (ushort*)alloc(65536 * 2);
    ushort* Pa2     = (ushort*)alloc(32768 * 2);
    // large optional buffer LAST so the fallback path never depends on it
    float* Weff     = (float*)alloc((size_t)BB * 128 * 80 * 4); // 83.9 MB
    bool useWeff = (off <= ws_size);
    (void)in_sizes; (void)n_in; (void)out_size;

    k_prep<<<160, 256, 0, stream>>>(attW0, attW1, W0T, Wk, Wd, WqmC, W1T);
    k_pack<<<384, 256, 0, stream>>>(gWih, gWhh, aWr, aWu, aWh, Pgru, Pa1, Pa2);
    k_hist<<<BB, 128, 0, stream>>>(hist, len, hsum);
    if (useWeff)
        k_weff<<<BB, 256, 0, stream>>>(item, Wk, Wd, WqmC, attb0, Weff, bias2);
    k_gru_mfma<<<256, 512, 0, stream>>>(hist, Pgru, gbih, gbhh, keys);
    if (useWeff)
        k_attn<<<(BB * TT) / 256, 256, 0, stream>>>(keys, Weff, bias2, W1T, attb1, attW2, attb2, scoreRaw);
    else
        k_attn4<<<(BB * TT) / 256, 256, 0, stream>>>(keys, item, W0T, attb0, W1T, attb1, attW2, attb2, scoreRaw);
    k_soft<<<BB, 128, 0, stream>>>(scoreRaw, len, keys, pooled);
    k_augru_mfma<<<256, 512, 0, stream>>>(keys, pooled, len, Pa1, Pa2, abr, abu, abh, attf);
    k_comb<<<(BB * 640) / 256, 256, 0, stream>>>(user, item, hsum, attf, comb);
    k_mlp<<<(BB * 200) / 256, 256, 0, stream>>>(comb, phW0, phb0, h1, 640, 200);
    k_mlp<<<(BB * 80) / 256, 256, 0, stream>>>(h1, phW1, phb1, h2, 200, 80);
    k_final<<<(BB + 255) / 256, 256, 0, stream>>>(h2, phW2, phb2, (float*)d_out);
}

// Round 4
// 724.491 us; speedup vs baseline: 6.7491x; 1.5533x over previous
//
#include <hip/hip_runtime.h>
#include <math.h>

#define BB 2048
#define TT 100
#define DD 128
#define HH 128

typedef __attribute__((ext_vector_type(8))) short bf16x8;
typedef __attribute__((ext_vector_type(4))) float f32x4;

__device__ __forceinline__ float sigm(float x) { return 1.f / (1.f + expf(-x)); }
__device__ __forceinline__ float tanh_fast(float x) {
    x = fminf(fmaxf(x, -15.f), 15.f);
    float e = expf(2.f * x);
    return (e - 1.f) / (e + 1.f);
}
__device__ __forceinline__ short f2bf(float f) {
    union { float f; unsigned u; } v; v.f = f;
    unsigned r = v.u + 0x7FFF + ((v.u >> 16) & 1);
    return (short)(r >> 16);
}
__device__ __forceinline__ float bf2f(ushort u) {
    union { unsigned u; float f; } v; v.u = ((unsigned)u) << 16;
    return v.f;
}

// ---------------- prep: attention layer0 factorization ----------------
// feat=[k,q,k-q,q*k] => score0 = k @ (W0a+W0c + q.*W0d) + (b0 + q@(W0b-W0c))
__global__ void k_prep(const float* __restrict__ attW0,
                       float* __restrict__ Wk, float* __restrict__ Wd, float* __restrict__ WqmC) {
    int i = blockIdx.x * 256 + threadIdx.x;
    if (i < 128 * 80) {
        int d = i / 80, j = i - d * 80;
        Wk[i]   = attW0[j * 512 + d] + attW0[j * 512 + 256 + d];
        Wd[i]   = attW0[j * 512 + 384 + d];
        WqmC[i] = attW0[j * 512 + 128 + d] - attW0[j * 512 + 256 + d];
    }
}

// ---------------- pack weights into MFMA B-fragment order (bf16) ----------------
// 16x16x32 B-fragment: value B[k][n] at lane li, elem e: n=li&15, k=(li>>4)*8+e (per 32-k tile).
__global__ void k_pack(const float* __restrict__ Wih, const float* __restrict__ Whh,
                       const float* __restrict__ Wr, const float* __restrict__ Wu, const float* __restrict__ Wh,
                       const float* __restrict__ attW1,
                       ushort* __restrict__ Pgru, ushort* __restrict__ Pa1, ushort* __restrict__ Pa2,
                       ushort* __restrict__ W1bf) {
    int n = blockIdx.x * 256 + threadIdx.x;
    if (n < 98304) { // GRU: 48 tiles (0..23 Wih cols, 24..47 Whh cols), 4 k-tiles
        int tile = n >> 11, kt = (n >> 9) & 3, li = (n >> 3) & 63, e = n & 7;
        int k = kt * 32 + (li >> 4) * 8 + e;
        float s;
        if (tile < 24) { int j = tile * 16 + (li & 15); s = Wih[j * 128 + k]; }
        else           { int j = (tile - 24) * 16 + (li & 15); s = Whh[j * 128 + k]; }
        Pgru[n] = (ushort)f2bf(s);
    }
    if (n < 65536) { // AUGRU P1: 16 tiles (cols: 0..127 r, 128..255 u), 8 k-tiles (k<128 h, >=128 x)
        int tile = n >> 12, kt = (n >> 9) & 7, li = (n >> 3) & 63, e = n & 7;
        int k = kt * 32 + (li >> 4) * 8 + e;
        int jj = tile * 16 + (li & 15);
        float s = (jj < 128) ? Wr[jj * 256 + k] : Wu[(jj - 128) * 256 + k];
        Pa1[n] = (ushort)f2bf(s);
    }
    if (n < 32768) { // AUGRU P2: 8 tiles (Wh cols), 8 k-tiles
        int tile = n >> 12, kt = (n >> 9) & 7, li = (n >> 3) & 63, e = n & 7;
        int k = kt * 32 + (li >> 4) * 8 + e;
        int j = tile * 16 + (li & 15);
        Pa2[n] = (ushort)f2bf(Wh[j * 256 + k]);
    }
    if (n < 4608) { // attention layer1: (K=80 pad 96) x (N=40 pad 48): 3 nt x 3 kt
        int nt = n >> 9; int rem = n & 511;
        int kt = nt % 3; nt /= 3;
        // recompute cleanly: flat = ((nt*3+kt)*64+li)*8+e
        int g = n >> 9;          // 0..8
        nt = g / 3; kt = g - nt * 3;
        int li = (rem >> 3) & 63, e = rem & 7;
        int k = kt * 32 + (li >> 4) * 8 + e;
        int j2 = nt * 16 + (li & 15);
        float s = (k < 80 && j2 < 40) ? attW1[j2 * 80 + k] : 0.f;
        W1bf[n] = (ushort)f2bf(s);
    }
}

// ---------------- per-b effective layer0 weights, bf16 fragment order ----------------
__global__ void k_weffbf(const float* __restrict__ item, const float* __restrict__ Wk,
                         const float* __restrict__ Wd, const float* __restrict__ WqmC,
                         const float* __restrict__ attb0,
                         ushort* __restrict__ Weffbf, float* __restrict__ bias2) {
    int b = blockIdx.x, tid = threadIdx.x;
    __shared__ float q[128];
    if (tid < 128) q[tid] = item[b * 128 + tid];
    __syncthreads();
    ushort* Wb = Weffbf + (size_t)b * 10240;
    for (int idx = tid; idx < 10240; idx += 256) {
        int e = idx & 7, li = (idx >> 3) & 63, kt = (idx >> 9) & 3, nt = idx >> 11;
        int d = kt * 32 + (li >> 4) * 8 + e;
        int j = nt * 16 + (li & 15);
        Wb[idx] = (ushort)f2bf(Wk[d * 80 + j] + q[d] * Wd[d * 80 + j]);
    }
    if (tid < 80) {
        float s = attb0[tid];
        for (int d = 0; d < 128; ++d) s += q[d] * WqmC[d * 80 + tid];
        bias2[b * 80 + tid] = s;
    }
}

// ---------------- GRU scan via MFMA (prefetch + fused hist_sum, bf16 keys out) ----------------
__global__ __launch_bounds__(512) void k_gru_mfma(const float* __restrict__ hist,
                                                  const ushort* __restrict__ Wp,
                                                  const float* __restrict__ bih, const float* __restrict__ bhh,
                                                  const int* __restrict__ len,
                                                  ushort* __restrict__ keysbf, float* __restrict__ hsum) {
    int tid = threadIdx.x;
    int lane = tid & 63, w = tid >> 6;
    int b0 = blockIdx.x * 8;

    __shared__ ushort xbf[16 * 128];   // bf16, swizzle: byte = row*256 + (off ^ ((row&7)<<4))
    __shared__ ushort hbf[16 * 128];
    __shared__ float  hs[8 * 128];
    __shared__ float  Glds[48 * 64 * 4];
    __shared__ int    ln[8];

    for (int e = tid; e < 16 * 128; e += 512) { xbf[e] = 0; hbf[e] = 0; }
    for (int e = tid; e < 8 * 128; e += 512) hs[e] = 0.f;
    if (tid < 8) ln[tid] = len[b0 + tid];

    bf16x8 bfrag[6][4];
#pragma unroll
    for (int f = 0; f < 6; ++f)
#pragma unroll
        for (int kt = 0; kt < 4; ++kt)
            bfrag[f][kt] = ((const bf16x8*)Wp)[((w * 6 + f) * 4 + kt) * 64 + lane];

    float bi0 = 0, bi1 = 0, bi2 = 0, bq0 = 0, bq1 = 0, bq2 = 0;
    int gd = tid & 127, grq = (tid >> 7) & 1;
    if (tid < 256) {
        bi0 = bih[gd]; bi1 = bih[128 + gd]; bi2 = bih[256 + gd];
        bq0 = bhh[gd]; bq1 = bhh[128 + gd]; bq2 = bhh[256 + gd];
    }
    __syncthreads();

    const ushort* Abuf = (w < 4) ? xbf : hbf;
    int arow = lane & 15, akg = lane >> 4;
    int srow = tid >> 6, sd0 = (tid & 63) * 2;
    int Lrow = ln[srow];
    const float* hsrc = &hist[(size_t)(b0 + srow) * TT * DD + sd0];
    float2 v = *(const float2*)hsrc;       // prefetched x_0
    float sum0 = 0.f, sum1 = 0.f;

    for (int t = 0; t < TT; ++t) {
        // stage prefetched x_t, issue load for t+1
        {
            unsigned pv = (unsigned)(unsigned short)f2bf(v.x) | ((unsigned)(unsigned short)f2bf(v.y) << 16);
            *(unsigned*)((char*)xbf + srow * 256 + ((sd0 * 2) ^ ((srow & 7) << 4))) = pv;
            if (t < Lrow) { sum0 += v.x; sum1 += v.y; }
            if (t + 1 < TT) v = *(const float2*)(hsrc + (size_t)(t + 1) * DD);
        }
        __syncthreads();

        // MFMA: 6 col-tiles x 4 k-tiles per wave
        {
            bf16x8 af[4];
#pragma unroll
            for (int kt = 0; kt < 4; ++kt) {
                int byte = (kt * 64 + akg * 16) ^ ((arow & 7) << 4);
                af[kt] = *(const bf16x8*)((const char*)Abuf + arow * 256 + byte);
            }
#pragma unroll
            for (int f = 0; f < 6; ++f) {
                f32x4 acc = {0.f, 0.f, 0.f, 0.f};
#pragma unroll
                for (int kt = 0; kt < 4; ++kt)
                    acc = __builtin_amdgcn_mfma_f32_16x16x32_bf16(af[kt], bfrag[f][kt], acc, 0, 0, 0);
                *(f32x4*)&Glds[((w * 6 + f) * 64 + lane) * 4] = acc;
            }
        }
        __syncthreads();

        // gates
        if (tid < 256) {
            int d = gd, rq = grq;
            int ti = d >> 4, lidx = rq * 16 + (d & 15);
            f32x4 gi0 = *(const f32x4*)&Glds[((ti) * 64 + lidx) * 4];
            f32x4 gi1 = *(const f32x4*)&Glds[((8 + ti) * 64 + lidx) * 4];
            f32x4 gi2 = *(const f32x4*)&Glds[((16 + ti) * 64 + lidx) * 4];
            f32x4 gh0 = *(const f32x4*)&Glds[((24 + ti) * 64 + lidx) * 4];
            f32x4 gh1 = *(const f32x4*)&Glds[((32 + ti) * 64 + lidx) * 4];
            f32x4 gh2 = *(const f32x4*)&Glds[((40 + ti) * 64 + lidx) * 4];
#pragma unroll
            for (int i = 0; i < 4; ++i) {
                int row = rq * 4 + i;
                float r = sigm(gi0[i] + bi0 + gh0[i] + bq0);
                float z = sigm(gi1[i] + bi1 + gh1[i] + bq1);
                float nn = tanh_fast(gi2[i] + bi2 + r * (gh2[i] + bq2));
                float hold = hs[row * 128 + d];
                float hnew = (1.f - z) * nn + z * hold;
                hs[row * 128 + d] = hnew;
                *(short*)((char*)hbf + row * 256 + ((d * 2) ^ ((row & 7) << 4))) = f2bf(hnew);
                keysbf[((size_t)(b0 + row) * TT + t) * HH + d] = (ushort)f2bf(hnew);
            }
        }
        __syncthreads();
    }

    hsum[(b0 + srow) * 128 + sd0]     = sum0 / (float)Lrow;
    hsum[(b0 + srow) * 128 + sd0 + 1] = sum1 / (float)Lrow;
}

// ---------------- fused attention MLP + masked softmax + pooled (one block per b) ----------------
// layer0: (112x128)@(128x80) MFMA vs per-b Weffbf; layer1: (112x96)@(96x48) MFMA; layer2+softmax+pooled in-block.
__global__ __launch_bounds__(512) void k_attnsoft(const ushort* __restrict__ keysbf,
                                                  const ushort* __restrict__ Weffbf,
                                                  const float* __restrict__ bias2,
                                                  const ushort* __restrict__ W1bf,
                                                  const float* __restrict__ attb1, const float* __restrict__ attW2,
                                                  const float* __restrict__ attb2,
                                                  const int* __restrict__ len,
                                                  float* __restrict__ pooled) {
    int tid = threadIdx.x;
    int lane = tid & 63, w = tid >> 6;
    int b = blockIdx.x;

    __shared__ ushort kbf[112 * 128];    // keys bf16 swizzled, stride 256B
    __shared__ ushort scbf[112 * 96];    // relu(layer0) bf16 swizzled, stride 192B
    __shared__ float  bias2s[80];
    __shared__ float  b1s[48];
    __shared__ float  W2s[48];
    __shared__ float  attn_s[128];
    __shared__ float  red[128];

    // preload B fragments (waves 0..6)
    bf16x8 bfrag0[5][4];
    bf16x8 bfrag1[3][3];
    if (w < 7) {
        const bf16x8* Wb = (const bf16x8*)(Weffbf + (size_t)b * 10240);
#pragma unroll
        for (int nt = 0; nt < 5; ++nt)
#pragma unroll
            for (int kt = 0; kt < 4; ++kt)
                bfrag0[nt][kt] = Wb[(nt * 4 + kt) * 64 + lane];
#pragma unroll
        for (int nt = 0; nt < 3; ++nt)
#pragma unroll
            for (int kt = 0; kt < 3; ++kt)
                bfrag1[nt][kt] = ((const bf16x8*)W1bf)[(nt * 3 + kt) * 64 + lane];
    }

    // stage keys -> kbf (rows 0..99; rows 100..111 zero)
    const ushort* ksrc = keysbf + (size_t)b * TT * 128;
    for (int e = tid; e < 3584; e += 512) {
        int row = e >> 5, c4 = e & 31;
        uint2 pv;
        if (row < TT) pv = *(const uint2*)(ksrc + row * 128 + c4 * 4);
        else { pv.x = 0; pv.y = 0; }
        *(uint2*)((char*)kbf + row * 256 + ((c4 * 8) ^ ((row & 7) << 4))) = pv;
    }
    // zero scbf pad cols 80..95 (avoid NaN garbage; B pad is zero but stay safe)
    for (int e = tid; e < 1792; e += 512) {
        int row = e >> 4, c = 80 + (e & 15);
        *(ushort*)((char*)scbf + row * 192 + ((c * 2) ^ ((row & 7) << 4))) = 0;
    }
    if (tid < 80) bias2s[tid] = bias2[b * 80 + tid];
    if (tid < 48) {
        b1s[tid] = (tid < 40) ? attb1[tid] : 0.f;
        W2s[tid] = (tid < 40) ? attW2[tid] : 0.f;
    }
    __syncthreads();

    // layer0 MFMA: wave w -> m-tile w (rows 16w..16w+15)
    if (w < 7) {
        int arow = lane & 15, akg = lane >> 4;
        int row = w * 16 + arow;
        bf16x8 af[4];
#pragma unroll
        for (int kt = 0; kt < 4; ++kt)
            af[kt] = *(const bf16x8*)((const char*)kbf + row * 256 + (((kt * 64 + akg * 16)) ^ ((row & 7) << 4)));
#pragma unroll
        for (int nt = 0; nt < 5; ++nt) {
            f32x4 acc = {0.f, 0.f, 0.f, 0.f};
#pragma unroll
            for (int kt = 0; kt < 4; ++kt)
                acc = __builtin_amdgcn_mfma_f32_16x16x32_bf16(af[kt], bfrag0[nt][kt], acc, 0, 0, 0);
            int col = nt * 16 + arow;
            float bcol = bias2s[col];
#pragma unroll
            for (int i = 0; i < 4; ++i) {
                int r2 = w * 16 + akg * 4 + i;
                float vsc = fmaxf(acc[i] + bcol, 0.f);
                *(short*)((char*)scbf + r2 * 192 + ((col * 2) ^ ((r2 & 7) << 4))) = f2bf(vsc);
            }
        }
    }
    __syncthreads();

    // layer1 MFMA + layer2 dot + relu
    if (w < 7) {
        int arow = lane & 15, akg = lane >> 4;
        int row = w * 16 + arow;
        bf16x8 a1[3];
#pragma unroll
        for (int kt = 0; kt < 3; ++kt)
            a1[kt] = *(const bf16x8*)((const char*)scbf + row * 192 + (((kt * 64 + akg * 16)) ^ ((row & 7) << 4)));
        float pi[4] = {0.f, 0.f, 0.f, 0.f};
#pragma unroll
        for (int nt = 0; nt < 3; ++nt) {
            f32x4 acc = {0.f, 0.f, 0.f, 0.f};
#pragma unroll
            for (int kt = 0; kt < 3; ++kt)
                acc = __builtin_amdgcn_mfma_f32_16x16x32_bf16(a1[kt], bfrag1[nt][kt], acc, 0, 0, 0);
            int col = nt * 16 + arow;
            float wb = W2s[col], bb1 = b1s[col];
#pragma unroll
            for (int i = 0; i < 4; ++i)
                pi[i] += fmaxf(acc[i] + bb1, 0.f) * wb;
        }
#pragma unroll
        for (int off = 1; off < 16; off <<= 1)
#pragma unroll
            for (int i = 0; i < 4; ++i)
                pi[i] += __shfl_xor(pi[i], off);
        if ((lane & 15) == 0) {
            float b2 = attb2[0];
#pragma unroll
            for (int i = 0; i < 4; ++i) {
                int t = w * 16 + akg * 4 + i;
                if (t < 128) attn_s[t] = fmaxf(pi[i] + b2, 0.f);
            }
        }
    }
    __syncthreads();

    // masked softmax over t<L, then pooled = attn @ keys
    int L = len[b];
    if (tid < 128) red[tid] = (tid < L) ? attn_s[tid] : -INFINITY;
    __syncthreads();
    for (int o = 64; o >= 1; o >>= 1) { if (tid < o) red[tid] = fmaxf(red[tid], red[tid + o]); __syncthreads(); }
    float mx = red[0];
    __syncthreads();
    if (tid < 128) {
        float e = (tid < L) ? expf(attn_s[tid] - mx) : 0.f;
        attn_s[tid] = e; red[tid] = e;
    }
    __syncthreads();
    for (int o = 64; o >= 1; o >>= 1) { if (tid < o) red[tid] += red[tid + o]; __syncthreads(); }
    float inv = 1.f / red[0];
    if (tid < 128) {
        int d = tid;
        float p = 0.f;
        for (int t2 = 0; t2 < L; ++t2) {
            ushort kv = *(const ushort*)((const char*)kbf + t2 * 256 + ((d * 2) ^ ((t2 & 7) << 4)));
            p += attn_s[t2] * bf2f(kv);
        }
        pooled[b * 128 + d] = p * inv;
    }
}

// ---------------- AUGRU scan via MFMA (prefetch, bf16 keys in) ----------------
__global__ __launch_bounds__(512) void k_augru_mfma(const ushort* __restrict__ keysbf,
                                                    const float* __restrict__ pooled,
                                                    const int* __restrict__ len,
                                                    const ushort* __restrict__ Wp1, const ushort* __restrict__ Wp2,
                                                    const float* __restrict__ br, const float* __restrict__ bu,
                                                    const float* __restrict__ bh,
                                                    float* __restrict__ att_feat) {
    int tid = threadIdx.x;
    int lane = tid & 63, w = tid >> 6;
    int b0 = blockIdx.x * 8;

    __shared__ ushort hbf[16 * 128], xbf[16 * 128], rhbf[16 * 128];
    __shared__ float hs[8 * 128];
    __shared__ float G1[16 * 64 * 4], G2[8 * 64 * 4];
    __shared__ float as_[8];
    __shared__ int ln[8];

    for (int e = tid; e < 16 * 128; e += 512) { hbf[e] = 0; xbf[e] = 0; rhbf[e] = 0; }
    for (int e = tid; e < 8 * 128; e += 512) hs[e] = 0.f;
    if (tid < 8) ln[tid] = len[b0 + tid];

    bf16x8 b1frag[2][8];
    bf16x8 b2frag[8];
#pragma unroll
    for (int f = 0; f < 2; ++f)
#pragma unroll
        for (int kt = 0; kt < 8; ++kt)
            b1frag[f][kt] = ((const bf16x8*)Wp1)[((w * 2 + f) * 8 + kt) * 64 + lane];
#pragma unroll
    for (int kt = 0; kt < 8; ++kt)
        b2frag[kt] = ((const bf16x8*)Wp2)[(w * 8 + kt) * 64 + lane];

    float brr = 0, buu = 0, bhh_ = 0;
    int gd = tid & 127, grq = (tid >> 7) & 1;
    if (tid < 256) { brr = br[gd]; buu = bu[gd]; bhh_ = bh[gd]; }
    __syncthreads();

    int arow = lane & 63 & 15, akg = lane >> 4;
    int srow = tid >> 6, sd0 = (tid & 63) * 2;
    const ushort* xsrc = &keysbf[(size_t)(b0 + srow) * TT * HH + sd0];
    unsigned v = *(const unsigned*)xsrc;               // prefetched x_0 (2 bf16)
    float areg = (tid < 8) ? pooled[(b0 + tid) * HH] : 0.f;

    for (int t = 0; t < TT; ++t) {
        // stage prefetched x_t and a_t; issue loads for t+1
        *(unsigned*)((char*)xbf + srow * 256 + ((sd0 * 2) ^ ((srow & 7) << 4))) = v;
        if (tid < 8) as_[tid] = areg;
        if (t + 1 < TT) {
            v = *(const unsigned*)(xsrc + (size_t)(t + 1) * HH);
            if (tid < 8) areg = pooled[(b0 + tid) * HH + t + 1];
        }
        __syncthreads();

        // P1 MFMA
        {
            bf16x8 af[8];
#pragma unroll
            for (int kt = 0; kt < 8; ++kt) {
                const ushort* buf = (kt < 4) ? hbf : xbf;
                int kk = kt & 3;
                int byte = (kk * 64 + akg * 16) ^ ((arow & 7) << 4);
                af[kt] = *(const bf16x8*)((const char*)buf + arow * 256 + byte);
            }
#pragma unroll
            for (int f = 0; f < 2; ++f) {
                f32x4 acc = {0.f, 0.f, 0.f, 0.f};
#pragma unroll
                for (int kt = 0; kt < 8; ++kt)
                    acc = __builtin_amdgcn_mfma_f32_16x16x32_bf16(af[kt], b1frag[f][kt], acc, 0, 0, 0);
                *(f32x4*)&G1[((w * 2 + f) * 64 + lane) * 4] = acc;
            }
        }
        __syncthreads();

        float u_reg[4], hold_reg[4];
        if (tid < 256) {
            int d = gd, rq = grq;
            int ti = d >> 4, lidx = rq * 16 + (d & 15);
            f32x4 gr = *(const f32x4*)&G1[((ti) * 64 + lidx) * 4];
            f32x4 gu = *(const f32x4*)&G1[((8 + ti) * 64 + lidx) * 4];
#pragma unroll
            for (int i = 0; i < 4; ++i) {
                int row = rq * 4 + i;
                float r = sigm(gr[i] + brr);
                float u = as_[row] * sigm(gu[i] + buu);
                float hold = hs[row * 128 + d];
                u_reg[i] = u; hold_reg[i] = hold;
                *(short*)((char*)rhbf + row * 256 + ((d * 2) ^ ((row & 7) << 4))) = f2bf(r * hold);
            }
        }
        __syncthreads();

        // P2 MFMA
        {
            bf16x8 af[8];
#pragma unroll
            for (int kt = 0; kt < 8; ++kt) {
                const ushort* buf = (kt < 4) ? rhbf : xbf;
                int kk = kt & 3;
                int byte = (kk * 64 + akg * 16) ^ ((arow & 7) << 4);
                af[kt] = *(const bf16x8*)((const char*)buf + arow * 256 + byte);
            }
            f32x4 acc = {0.f, 0.f, 0.f, 0.f};
#pragma unroll
            for (int kt = 0; kt < 8; ++kt)
                acc = __builtin_amdgcn_mfma_f32_16x16x32_bf16(af[kt], b2frag[kt], acc, 0, 0, 0);
            *(f32x4*)&G2[(w * 64 + lane) * 4] = acc;
        }
        __syncthreads();

        if (tid < 256) {
            int d = gd, rq = grq;
            int ti = d >> 4, lidx = rq * 16 + (d & 15);
            f32x4 g2 = *(const f32x4*)&G2[(ti * 64 + lidx) * 4];
#pragma unroll
            for (int i = 0; i < 4; ++i) {
                int row = rq * 4 + i;
                float hhat = tanh_fast(g2[i] + bhh_);
                float u = u_reg[i];
                float hnew = (1.f - u) * hold_reg[i] + u * hhat;
                hs[row * 128 + d] = hnew;
                *(short*)((char*)hbf + row * 256 + ((d * 2) ^ ((row & 7) << 4))) = f2bf(hnew);
                if (t == ln[row] - 1) att_feat[(b0 + row) * HH + d] = hnew;
            }
        }
        __syncthreads();
    }
}

// ---------------- comb build ----------------
__global__ void k_comb(const float* __restrict__ user, const float* __restrict__ item,
                       const float* __restrict__ hsum, const float* __restrict__ attf,
                       float* __restrict__ comb) {
    int gid = blockIdx.x * 256 + threadIdx.x;
    if (gid >= BB * 640) return;
    int b = gid / 640, c = gid - b * 640;
    float v;
    if (c < 128) v = user[b * 128 + c];
    else if (c < 256) v = item[b * 128 + (c - 128)];
    else if (c < 384) v = hsum[b * 128 + (c - 256)];
    else if (c < 512) { int d = c - 384; v = item[b * 128 + d] * hsum[b * 128 + d]; }
    else v = attf[b * 128 + (c - 512)];
    comb[gid] = v;
}

// ---------------- generic sigmoid MLP layer ----------------
__global__ void k_mlp(const float* __restrict__ in, const float* __restrict__ W, const float* __restrict__ bias,
                      float* __restrict__ out, int K, int N) {
    int gid = blockIdx.x * 256 + threadIdx.x;
    if (gid >= BB * N) return;
    int b = gid / N, j = gid - b * N;
    const float* ip = in + (size_t)b * K;
    const float* wp = W + (size_t)j * K;
    float acc = bias[j];
    for (int kc = 0; kc < K / 4; ++kc) {
        float4 x = *(const float4*)(ip + kc * 4);
        float4 w = *(const float4*)(wp + kc * 4);
        acc += x.x * w.x + x.y * w.y + x.z * w.z + x.w * w.w;
    }
    out[(size_t)b * N + j] = sigm(acc);
}

// ---------------- final layer 80->1 ----------------
__global__ void k_final(const float* __restrict__ h2, const float* __restrict__ W, const float* __restrict__ bias,
                        float* __restrict__ out) {
    int b = blockIdx.x * 256 + threadIdx.x;
    if (b >= BB) return;
    const float* ip = h2 + (size_t)b * 80;
    float acc = bias[0];
    for (int k = 0; k < 80; ++k) acc += ip[k] * W[k];
    out[b] = sigm(acc);
}

extern "C" void kernel_launch(void* const* d_in, const int* in_sizes, int n_in,
                              void* d_out, int out_size, void* d_ws, size_t ws_size,
                              hipStream_t stream) {
    const float* user = (const float*)d_in[0];
    const float* hist = (const float*)d_in[1];
    const float* item = (const float*)d_in[2];
    const int* len = (const int*)d_in[4];
    const float* gWih = (const float*)d_in[5];
    const float* gWhh = (const float*)d_in[6];
    const float* gbih = (const float*)d_in[7];
    const float* gbhh = (const float*)d_in[8];
    const float* aWr = (const float*)d_in[9];
    const float* abr = (const float*)d_in[10];
    const float* aWu = (const float*)d_in[11];
    const float* abu = (const float*)d_in[12];
    const float* aWh = (const float*)d_in[13];
    const float* abh = (const float*)d_in[14];
    const float* attW0 = (const float*)d_in[15];
    const float* attb0 = (const float*)d_in[16];
    const float* attW1 = (const float*)d_in[17];
    const float* attb1 = (const float*)d_in[18];
    const float* attW2 = (const float*)d_in[19];
    const float* attb2 = (const float*)d_in[20];
    const float* phW0 = (const float*)d_in[21];
    const float* phb0 = (const float*)d_in[22];
    const float* phW1 = (const float*)d_in[23];
    const float* phb1 = (const float*)d_in[24];
    const float* phW2 = (const float*)d_in[25];
    const float* phb2 = (const float*)d_in[26];

    char* ws = (char*)d_ws;
    size_t off = 0;
    auto alloc = [&](size_t bytes) { char* p = ws + off; off += (bytes + 255) & ~(size_t)255; return p; };
    ushort* keysbf  = (ushort*)alloc((size_t)BB * TT * HH * 2);   // 52.4 MB
    ushort* Weffbf  = (ushort*)alloc((size_t)BB * 10240 * 2);     // 41.9 MB
    float* pooled   = (float*)alloc((size_t)BB * HH * 4);
    float* hsum     = (float*)alloc((size_t)BB * DD * 4);
    float* attf     = (float*)alloc((size_t)BB * HH * 4);
    float* comb     = (float*)alloc((size_t)BB * 640 * 4);
    float* h1       = (float*)alloc((size_t)BB * 200 * 4);
    float* h2       = (float*)alloc((size_t)BB * 80 * 4);
    float* Wk       = (float*)alloc(128 * 80 * 4);
    float* Wd       = (float*)alloc(128 * 80 * 4);
    float* WqmC     = (float*)alloc(128 * 80 * 4);
    float* bias2    = (float*)alloc((size_t)BB * 80 * 4);
    ushort* Pgru    = (ushort*)alloc(98304 * 2);
    ushort* Pa1     = (ushort*)alloc(65536 * 2);
    ushort* Pa2     = (ushort*)alloc(32768 * 2);
    ushort* W1bf    = (ushort*)alloc(4608 * 2);
    (void)in_sizes; (void)n_in; (void)out_size; (void)ws_size;

    k_prep<<<40, 256, 0, stream>>>(attW0, Wk, Wd, WqmC);
    k_pack<<<384, 256, 0, stream>>>(gWih, gWhh, aWr, aWu, aWh, attW1, Pgru, Pa1, Pa2, W1bf);
    k_weffbf<<<BB, 256, 0, stream>>>(item, Wk, Wd, WqmC, attb0, Weffbf, bias2);
    k_gru_mfma<<<256, 512, 0, stream>>>(hist, Pgru, gbih, gbhh, len, keysbf, hsum);
    k_attnsoft<<<BB, 512, 0, stream>>>(keysbf, Weffbf, bias2, W1bf, attb1, attW2, attb2, len, pooled);
    k_augru_mfma<<<256, 512, 0, stream>>>(keysbf, pooled, len, Pa1, Pa2, abr, abu, abh, attf);
    k_comb<<<(BB * 640) / 256, 256, 0, stream>>>(user, item, hsum, attf, comb);
    k_mlp<<<(BB * 200) / 256, 256, 0, stream>>>(comb, phW0, phb0, h1, 640, 200);
    k_mlp<<<(BB * 80) / 256, 256, 0, stream>>>(h1, phW1, phb1, h2, 200, 80);
    k_final<<<(BB + 255) / 256, 256, 0, stream>>>(h2, phW2, phb2, (float*)d_out);
}

// Round 5
// 540.400 us; speedup vs baseline: 9.0482x; 1.3407x over previous
//
#include <hip/hip_runtime.h>
#include <math.h>

#define BB 2048
#define TT 100
#define DD 128
#define HH 128

typedef __attribute__((ext_vector_type(8))) short bf16x8;
typedef __attribute__((ext_vector_type(4))) float f32x4;

__device__ __forceinline__ float sigm(float x) { return 1.f / (1.f + expf(-x)); }
__device__ __forceinline__ float tanh_fast(float x) {
    x = fminf(fmaxf(x, -15.f), 15.f);
    float e = expf(2.f * x);
    return (e - 1.f) / (e + 1.f);
}
__device__ __forceinline__ short f2bf(float f) {
    union { float f; unsigned u; } v; v.f = f;
    unsigned r = v.u + 0x7FFF + ((v.u >> 16) & 1);
    return (short)(r >> 16);
}
__device__ __forceinline__ float bf2f(ushort u) {
    union { unsigned u; float f; } v; v.u = ((unsigned)u) << 16;
    return v.f;
}

// ---------------- prep: attention layer0 factorization ----------------
__global__ void k_prep(const float* __restrict__ attW0,
                       float* __restrict__ Wk, float* __restrict__ Wd, float* __restrict__ WqmC) {
    int i = blockIdx.x * 256 + threadIdx.x;
    if (i < 128 * 80) {
        int d = i / 80, j = i - d * 80;
        Wk[i]   = attW0[j * 512 + d] + attW0[j * 512 + 256 + d];
        Wd[i]   = attW0[j * 512 + 384 + d];
        WqmC[i] = attW0[j * 512 + 128 + d] - attW0[j * 512 + 256 + d];
    }
}

// ---------------- pack weights into MFMA B-fragment order (bf16) ----------------
// 16x16x32 B-fragment: B[k][n] at lane li, elem e: n=li&15, k=(li>>4)*8+e (per 32-k tile).
__global__ void k_pack(const float* __restrict__ Wih, const float* __restrict__ Whh,
                       const float* __restrict__ Wr, const float* __restrict__ Wu, const float* __restrict__ Wh,
                       const float* __restrict__ attW1,
                       const float* __restrict__ phW0, const float* __restrict__ phW1,
                       ushort* __restrict__ Pgru, ushort* __restrict__ Pa1, ushort* __restrict__ Pa2,
                       ushort* __restrict__ W1bf, ushort* __restrict__ W0h, ushort* __restrict__ W1h) {
    int n = blockIdx.x * 256 + threadIdx.x;
    if (n < 98304) { // GRU: 48 tiles (0..23 Wih cols, 24..47 Whh cols), 4 k-tiles
        int tile = n >> 11, kt = (n >> 9) & 3, li = (n >> 3) & 63, e = n & 7;
        int k = kt * 32 + (li >> 4) * 8 + e;
        float s;
        if (tile < 24) { int j = tile * 16 + (li & 15); s = Wih[j * 128 + k]; }
        else           { int j = (tile - 24) * 16 + (li & 15); s = Whh[j * 128 + k]; }
        Pgru[n] = (ushort)f2bf(s);
    }
    if (n < 65536) { // AUGRU P1: 16 tiles (cols: 0..127 r, 128..255 u), 8 k-tiles
        int tile = n >> 12, kt = (n >> 9) & 7, li = (n >> 3) & 63, e = n & 7;
        int k = kt * 32 + (li >> 4) * 8 + e;
        int jj = tile * 16 + (li & 15);
        float s = (jj < 128) ? Wr[jj * 256 + k] : Wu[(jj - 128) * 256 + k];
        Pa1[n] = (ushort)f2bf(s);
    }
    if (n < 32768) { // AUGRU P2: 8 tiles (Wh cols), 8 k-tiles
        int tile = n >> 12, kt = (n >> 9) & 7, li = (n >> 3) & 63, e = n & 7;
        int k = kt * 32 + (li >> 4) * 8 + e;
        int j = tile * 16 + (li & 15);
        Pa2[n] = (ushort)f2bf(Wh[j * 256 + k]);
    }
    if (n < 4608) { // attention layer1: 3 nt x 3 kt (K=80->96, N=40->48)
        int g = n >> 9;
        int nt = g / 3, kt = g - nt * 3;
        int li = (n >> 3) & 63, e = n & 7;
        int k = kt * 32 + (li >> 4) * 8 + e;
        int j2 = nt * 16 + (li & 15);
        float s = (k < 80 && j2 < 40) ? attW1[j2 * 80 + k] : 0.f;
        W1bf[n] = (ushort)f2bf(s);
    }
    if (n < 133120) { // predict-head layer0: 13 nt x 20 kt (N=200->208, K=640)
        int g = n >> 9;
        int nt = g / 20, kt = g - nt * 20;
        int li = (n >> 3) & 63, e = n & 7;
        int k = kt * 32 + (li >> 4) * 8 + e;
        int j = nt * 16 + (li & 15);
        W0h[n] = (ushort)f2bf((j < 200) ? phW0[j * 640 + k] : 0.f);
    }
    if (n < 17920) { // predict-head layer1: 5 nt x 7 kt (N=80, K=200->224)
        int g = n >> 9;
        int nt = g / 7, kt = g - nt * 7;
        int li = (n >> 3) & 63, e = n & 7;
        int k = kt * 32 + (li >> 4) * 8 + e;
        int j = nt * 16 + (li & 15);
        W1h[n] = (ushort)f2bf((k < 200 && j < 80) ? phW1[j * 200 + k] : 0.f);
    }
}

// ---------------- per-b effective layer0 weights, bf16 fragment order ----------------
__global__ void k_weffbf(const float* __restrict__ item, const float* __restrict__ Wk,
                         const float* __restrict__ Wd, const float* __restrict__ WqmC,
                         const float* __restrict__ attb0,
                         ushort* __restrict__ Weffbf, float* __restrict__ bias2) {
    int b = blockIdx.x, tid = threadIdx.x;
    __shared__ float q[128];
    if (tid < 128) q[tid] = item[b * 128 + tid];
    __syncthreads();
    ushort* Wb = Weffbf + (size_t)b * 10240;
    for (int idx = tid; idx < 10240; idx += 256) {
        int e = idx & 7, li = (idx >> 3) & 63, kt = (idx >> 9) & 3, nt = idx >> 11;
        int d = kt * 32 + (li >> 4) * 8 + e;
        int j = nt * 16 + (li & 15);
        Wb[idx] = (ushort)f2bf(Wk[d * 80 + j] + q[d] * Wd[d * 80 + j]);
    }
    if (tid < 80) {
        float s = attb0[tid];
        for (int d = 0; d < 128; ++d) s += q[d] * WqmC[d * 80 + tid];
        bias2[b * 80 + tid] = s;
    }
}

// ---------------- GRU scan via MFMA (prefetch + fused hist_sum, bf16 keys out) ----------------
__global__ __launch_bounds__(512) void k_gru_mfma(const float* __restrict__ hist,
                                                  const ushort* __restrict__ Wp,
                                                  const float* __restrict__ bih, const float* __restrict__ bhh,
                                                  const int* __restrict__ len,
                                                  ushort* __restrict__ keysbf, float* __restrict__ hsum) {
    int tid = threadIdx.x;
    int lane = tid & 63, w = tid >> 6;
    int b0 = blockIdx.x * 8;

    __shared__ ushort xbf[16 * 128];   // bf16, swizzle: byte = row*256 + (off ^ ((row&7)<<4))
    __shared__ ushort hbf[16 * 128];
    __shared__ float  hs[8 * 128];
    __shared__ float  Glds[48 * 64 * 4];
    __shared__ int    ln[8];

    for (int e = tid; e < 16 * 128; e += 512) { xbf[e] = 0; hbf[e] = 0; }
    for (int e = tid; e < 8 * 128; e += 512) hs[e] = 0.f;
    if (tid < 8) ln[tid] = len[b0 + tid];

    bf16x8 bfrag[6][4];
#pragma unroll
    for (int f = 0; f < 6; ++f)
#pragma unroll
        for (int kt = 0; kt < 4; ++kt)
            bfrag[f][kt] = ((const bf16x8*)Wp)[((w * 6 + f) * 4 + kt) * 64 + lane];

    float bi0 = 0, bi1 = 0, bi2 = 0, bq0 = 0, bq1 = 0, bq2 = 0;
    int gd = tid & 127, grq = (tid >> 7) & 1;
    if (tid < 256) {
        bi0 = bih[gd]; bi1 = bih[128 + gd]; bi2 = bih[256 + gd];
        bq0 = bhh[gd]; bq1 = bhh[128 + gd]; bq2 = bhh[256 + gd];
    }
    __syncthreads();

    const ushort* Abuf = (w < 4) ? xbf : hbf;
    int arow = lane & 15, akg = lane >> 4;
    int srow = tid >> 6, sd0 = (tid & 63) * 2;
    int Lrow = ln[srow];
    const float* hsrc = &hist[(size_t)(b0 + srow) * TT * DD + sd0];
    float2 v = *(const float2*)hsrc;       // prefetched x_0
    float sum0 = 0.f, sum1 = 0.f;

    for (int t = 0; t < TT; ++t) {
        {
            unsigned pv = (unsigned)(unsigned short)f2bf(v.x) | ((unsigned)(unsigned short)f2bf(v.y) << 16);
            *(unsigned*)((char*)xbf + srow * 256 + ((sd0 * 2) ^ ((srow & 7) << 4))) = pv;
            if (t < Lrow) { sum0 += v.x; sum1 += v.y; }
            if (t + 1 < TT) v = *(const float2*)(hsrc + (size_t)(t + 1) * DD);
        }
        __syncthreads();

        {
            bf16x8 af[4];
#pragma unroll
            for (int kt = 0; kt < 4; ++kt) {
                int byte = (kt * 64 + akg * 16) ^ ((arow & 7) << 4);
                af[kt] = *(const bf16x8*)((const char*)Abuf + arow * 256 + byte);
            }
#pragma unroll
            for (int f = 0; f < 6; ++f) {
                f32x4 acc = {0.f, 0.f, 0.f, 0.f};
#pragma unroll
                for (int kt = 0; kt < 4; ++kt)
                    acc = __builtin_amdgcn_mfma_f32_16x16x32_bf16(af[kt], bfrag[f][kt], acc, 0, 0, 0);
                *(f32x4*)&Glds[((w * 6 + f) * 64 + lane) * 4] = acc;
            }
        }
        __syncthreads();

        if (tid < 256) {
            int d = gd, rq = grq;
            int ti = d >> 4, lidx = rq * 16 + (d & 15);
            f32x4 gi0 = *(const f32x4*)&Glds[((ti) * 64 + lidx) * 4];
            f32x4 gi1 = *(const f32x4*)&Glds[((8 + ti) * 64 + lidx) * 4];
            f32x4 gi2 = *(const f32x4*)&Glds[((16 + ti) * 64 + lidx) * 4];
            f32x4 gh0 = *(const f32x4*)&Glds[((24 + ti) * 64 + lidx) * 4];
            f32x4 gh1 = *(const f32x4*)&Glds[((32 + ti) * 64 + lidx) * 4];
            f32x4 gh2 = *(const f32x4*)&Glds[((40 + ti) * 64 + lidx) * 4];
#pragma unroll
            for (int i = 0; i < 4; ++i) {
                int row = rq * 4 + i;
                float r = sigm(gi0[i] + bi0 + gh0[i] + bq0);
                float z = sigm(gi1[i] + bi1 + gh1[i] + bq1);
                float nn = tanh_fast(gi2[i] + bi2 + r * (gh2[i] + bq2));
                float hold = hs[row * 128 + d];
                float hnew = (1.f - z) * nn + z * hold;
                hs[row * 128 + d] = hnew;
                *(short*)((char*)hbf + row * 256 + ((d * 2) ^ ((row & 7) << 4))) = f2bf(hnew);
                keysbf[((size_t)(b0 + row) * TT + t) * HH + d] = (ushort)f2bf(hnew);
            }
        }
        __syncthreads();
    }

    hsum[(b0 + srow) * 128 + sd0]     = sum0 / (float)Lrow;
    hsum[(b0 + srow) * 128 + sd0 + 1] = sum1 / (float)Lrow;
}

// ---------------- fused attention MLP + masked softmax + pooled (one block per b) ----------------
__global__ __launch_bounds__(512) void k_attnsoft(const ushort* __restrict__ keysbf,
                                                  const ushort* __restrict__ Weffbf,
                                                  const float* __restrict__ bias2,
                                                  const ushort* __restrict__ W1bf,
                                                  const float* __restrict__ attb1, const float* __restrict__ attW2,
                                                  const float* __restrict__ attb2,
                                                  const int* __restrict__ len,
                                                  float* __restrict__ pooled) {
    int tid = threadIdx.x;
    int lane = tid & 63, w = tid >> 6;
    int b = blockIdx.x;

    __shared__ ushort kbf[112 * 128];
    __shared__ ushort scbf[112 * 96];
    __shared__ float  bias2s[80];
    __shared__ float  b1s[48];
    __shared__ float  W2s[48];
    __shared__ float  attn_s[128];
    __shared__ float  red[128];

    bf16x8 bfrag0[5][4];
    bf16x8 bfrag1[3][3];
    if (w < 7) {
        const bf16x8* Wb = (const bf16x8*)(Weffbf + (size_t)b * 10240);
#pragma unroll
        for (int nt = 0; nt < 5; ++nt)
#pragma unroll
            for (int kt = 0; kt < 4; ++kt)
                bfrag0[nt][kt] = Wb[(nt * 4 + kt) * 64 + lane];
#pragma unroll
        for (int nt = 0; nt < 3; ++nt)
#pragma unroll
            for (int kt = 0; kt < 3; ++kt)
                bfrag1[nt][kt] = ((const bf16x8*)W1bf)[(nt * 3 + kt) * 64 + lane];
    }

    const ushort* ksrc = keysbf + (size_t)b * TT * 128;
    for (int e = tid; e < 3584; e += 512) {
        int row = e >> 5, c4 = e & 31;
        uint2 pv;
        if (row < TT) pv = *(const uint2*)(ksrc + row * 128 + c4 * 4);
        else { pv.x = 0; pv.y = 0; }
        *(uint2*)((char*)kbf + row * 256 + ((c4 * 8) ^ ((row & 7) << 4))) = pv;
    }
    for (int e = tid; e < 1792; e += 512) {
        int row = e >> 4, c = 80 + (e & 15);
        *(ushort*)((char*)scbf + row * 192 + ((c * 2) ^ ((row & 7) << 4))) = 0;
    }
    if (tid < 80) bias2s[tid] = bias2[b * 80 + tid];
    if (tid < 48) {
        b1s[tid] = (tid < 40) ? attb1[tid] : 0.f;
        W2s[tid] = (tid < 40) ? attW2[tid] : 0.f;
    }
    __syncthreads();

    if (w < 7) {
        int arow = lane & 15, akg = lane >> 4;
        int row = w * 16 + arow;
        bf16x8 af[4];
#pragma unroll
        for (int kt = 0; kt < 4; ++kt)
            af[kt] = *(const bf16x8*)((const char*)kbf + row * 256 + (((kt * 64 + akg * 16)) ^ ((row & 7) << 4)));
#pragma unroll
        for (int nt = 0; nt < 5; ++nt) {
            f32x4 acc = {0.f, 0.f, 0.f, 0.f};
#pragma unroll
            for (int kt = 0; kt < 4; ++kt)
                acc = __builtin_amdgcn_mfma_f32_16x16x32_bf16(af[kt], bfrag0[nt][kt], acc, 0, 0, 0);
            int col = nt * 16 + arow;
            float bcol = bias2s[col];
#pragma unroll
            for (int i = 0; i < 4; ++i) {
                int r2 = w * 16 + akg * 4 + i;
                float vsc = fmaxf(acc[i] + bcol, 0.f);
                *(short*)((char*)scbf + r2 * 192 + ((col * 2) ^ ((r2 & 7) << 4))) = f2bf(vsc);
            }
        }
    }
    __syncthreads();

    if (w < 7) {
        int arow = lane & 15, akg = lane >> 4;
        int row = w * 16 + arow;
        bf16x8 a1[3];
#pragma unroll
        for (int kt = 0; kt < 3; ++kt)
            a1[kt] = *(const bf16x8*)((const char*)scbf + row * 192 + (((kt * 64 + akg * 16)) ^ ((row & 7) << 4)));
        float pi[4] = {0.f, 0.f, 0.f, 0.f};
#pragma unroll
        for (int nt = 0; nt < 3; ++nt) {
            f32x4 acc = {0.f, 0.f, 0.f, 0.f};
#pragma unroll
            for (int kt = 0; kt < 3; ++kt)
                acc = __builtin_amdgcn_mfma_f32_16x16x32_bf16(a1[kt], bfrag1[nt][kt], acc, 0, 0, 0);
            int col = nt * 16 + arow;
            float wb = W2s[col], bb1 = b1s[col];
#pragma unroll
            for (int i = 0; i < 4; ++i)
                pi[i] += fmaxf(acc[i] + bb1, 0.f) * wb;
        }
#pragma unroll
        for (int off = 1; off < 16; off <<= 1)
#pragma unroll
            for (int i = 0; i < 4; ++i)
                pi[i] += __shfl_xor(pi[i], off);
        if ((lane & 15) == 0) {
            float b2 = attb2[0];
#pragma unroll
            for (int i = 0; i < 4; ++i) {
                int t = w * 16 + akg * 4 + i;
                if (t < 128) attn_s[t] = fmaxf(pi[i] + b2, 0.f);
            }
        }
    }
    __syncthreads();

    int L = len[b];
    if (tid < 128) red[tid] = (tid < L) ? attn_s[tid] : -INFINITY;
    __syncthreads();
    for (int o = 64; o >= 1; o >>= 1) { if (tid < o) red[tid] = fmaxf(red[tid], red[tid + o]); __syncthreads(); }
    float mx = red[0];
    __syncthreads();
    if (tid < 128) {
        float e = (tid < L) ? expf(attn_s[tid] - mx) : 0.f;
        attn_s[tid] = e; red[tid] = e;
    }
    __syncthreads();
    for (int o = 64; o >= 1; o >>= 1) { if (tid < o) red[tid] += red[tid + o]; __syncthreads(); }
    float inv = 1.f / red[0];
    if (tid < 128) {
        int d = tid;
        float p = 0.f;
        for (int t2 = 0; t2 < L; ++t2) {
            ushort kv = *(const ushort*)((const char*)kbf + t2 * 256 + ((d * 2) ^ ((t2 & 7) << 4)));
            p += attn_s[t2] * bf2f(kv);
        }
        pooled[b * 128 + d] = p * inv;
    }
}

// ---------------- AUGRU scan via MFMA (prefetch, bf16 keys in) ----------------
__global__ __launch_bounds__(512) void k_augru_mfma(const ushort* __restrict__ keysbf,
                                                    const float* __restrict__ pooled,
                                                    const int* __restrict__ len,
                                                    const ushort* __restrict__ Wp1, const ushort* __restrict__ Wp2,
                                                    const float* __restrict__ br, const float* __restrict__ bu,
                                                    const float* __restrict__ bh,
                                                    float* __restrict__ att_feat) {
    int tid = threadIdx.x;
    int lane = tid & 63, w = tid >> 6;
    int b0 = blockIdx.x * 8;

    __shared__ ushort hbf[16 * 128], xbf[16 * 128], rhbf[16 * 128];
    __shared__ float hs[8 * 128];
    __shared__ float G1[16 * 64 * 4], G2[8 * 64 * 4];
    __shared__ float as_[8];
    __shared__ int ln[8];

    for (int e = tid; e < 16 * 128; e += 512) { hbf[e] = 0; xbf[e] = 0; rhbf[e] = 0; }
    for (int e = tid; e < 8 * 128; e += 512) hs[e] = 0.f;
    if (tid < 8) ln[tid] = len[b0 + tid];

    bf16x8 b1frag[2][8];
    bf16x8 b2frag[8];
#pragma unroll
    for (int f = 0; f < 2; ++f)
#pragma unroll
        for (int kt = 0; kt < 8; ++kt)
            b1frag[f][kt] = ((const bf16x8*)Wp1)[((w * 2 + f) * 8 + kt) * 64 + lane];
#pragma unroll
    for (int kt = 0; kt < 8; ++kt)
        b2frag[kt] = ((const bf16x8*)Wp2)[(w * 8 + kt) * 64 + lane];

    float brr = 0, buu = 0, bhh_ = 0;
    int gd = tid & 127, grq = (tid >> 7) & 1;
    if (tid < 256) { brr = br[gd]; buu = bu[gd]; bhh_ = bh[gd]; }
    __syncthreads();

    int arow = lane & 15, akg = lane >> 4;
    int srow = tid >> 6, sd0 = (tid & 63) * 2;
    const ushort* xsrc = &keysbf[(size_t)(b0 + srow) * TT * HH + sd0];
    unsigned v = *(const unsigned*)xsrc;
    float areg = (tid < 8) ? pooled[(b0 + tid) * HH] : 0.f;

    for (int t = 0; t < TT; ++t) {
        *(unsigned*)((char*)xbf + srow * 256 + ((sd0 * 2) ^ ((srow & 7) << 4))) = v;
        if (tid < 8) as_[tid] = areg;
        if (t + 1 < TT) {
            v = *(const unsigned*)(xsrc + (size_t)(t + 1) * HH);
            if (tid < 8) areg = pooled[(b0 + tid) * HH + t + 1];
        }
        __syncthreads();

        {
            bf16x8 af[8];
#pragma unroll
            for (int kt = 0; kt < 8; ++kt) {
                const ushort* buf = (kt < 4) ? hbf : xbf;
                int kk = kt & 3;
                int byte = (kk * 64 + akg * 16) ^ ((arow & 7) << 4);
                af[kt] = *(const bf16x8*)((const char*)buf + arow * 256 + byte);
            }
#pragma unroll
            for (int f = 0; f < 2; ++f) {
                f32x4 acc = {0.f, 0.f, 0.f, 0.f};
#pragma unroll
                for (int kt = 0; kt < 8; ++kt)
                    acc = __builtin_amdgcn_mfma_f32_16x16x32_bf16(af[kt], b1frag[f][kt], acc, 0, 0, 0);
                *(f32x4*)&G1[((w * 2 + f) * 64 + lane) * 4] = acc;
            }
        }
        __syncthreads();

        float u_reg[4], hold_reg[4];
        if (tid < 256) {
            int d = gd, rq = grq;
            int ti = d >> 4, lidx = rq * 16 + (d & 15);
            f32x4 gr = *(const f32x4*)&G1[((ti) * 64 + lidx) * 4];
            f32x4 gu = *(const f32x4*)&G1[((8 + ti) * 64 + lidx) * 4];
#pragma unroll
            for (int i = 0; i < 4; ++i) {
                int row = rq * 4 + i;
                float r = sigm(gr[i] + brr);
                float u = as_[row] * sigm(gu[i] + buu);
                float hold = hs[row * 128 + d];
                u_reg[i] = u; hold_reg[i] = hold;
                *(short*)((char*)rhbf + row * 256 + ((d * 2) ^ ((row & 7) << 4))) = f2bf(r * hold);
            }
        }
        __syncthreads();

        {
            bf16x8 af[8];
#pragma unroll
            for (int kt = 0; kt < 8; ++kt) {
                const ushort* buf = (kt < 4) ? rhbf : xbf;
                int kk = kt & 3;
                int byte = (kk * 64 + akg * 16) ^ ((arow & 7) << 4);
                af[kt] = *(const bf16x8*)((const char*)buf + arow * 256 + byte);
            }
            f32x4 acc = {0.f, 0.f, 0.f, 0.f};
#pragma unroll
            for (int kt = 0; kt < 8; ++kt)
                acc = __builtin_amdgcn_mfma_f32_16x16x32_bf16(af[kt], b2frag[kt], acc, 0, 0, 0);
            *(f32x4*)&G2[(w * 64 + lane) * 4] = acc;
        }
        __syncthreads();

        if (tid < 256) {
            int d = gd, rq = grq;
            int ti = d >> 4, lidx = rq * 16 + (d & 15);
            f32x4 g2 = *(const f32x4*)&G2[(ti * 64 + lidx) * 4];
#pragma unroll
            for (int i = 0; i < 4; ++i) {
                int row = rq * 4 + i;
                float hhat = tanh_fast(g2[i] + bhh_);
                float u = u_reg[i];
                float hnew = (1.f - u) * hold_reg[i] + u * hhat;
                hs[row * 128 + d] = hnew;
                *(short*)((char*)hbf + row * 256 + ((d * 2) ^ ((row & 7) << 4))) = f2bf(hnew);
                if (t == ln[row] - 1) att_feat[(b0 + row) * HH + d] = hnew;
            }
        }
        __syncthreads();
    }
}

// ---------------- fused predict head: comb -> 200 -> 80 -> 1, all sigmoid ----------------
// 128 blocks x 1 wave; block handles 16 batch rows. MFMA 16x16x32 against pre-packed W0h/W1h.
__global__ __launch_bounds__(64) void k_head(const float* __restrict__ user, const float* __restrict__ item,
                                             const float* __restrict__ hsum, const float* __restrict__ attf,
                                             const ushort* __restrict__ W0h, const ushort* __restrict__ W1h,
                                             const float* __restrict__ phb0, const float* __restrict__ phb1,
                                             const float* __restrict__ phW2, const float* __restrict__ phb2,
                                             float* __restrict__ out) {
    int lane = threadIdx.x;
    int b0 = blockIdx.x * 16;
    __shared__ ushort xb[16 * 128];     // comb chunk, stride 256B, swizzled
    __shared__ ushort h1b[16 * 256];    // h1 (200 cols, pad), stride 512B, swizzled

    for (int e = lane; e < 4096; e += 64) h1b[e] = 0;

    int arow = lane & 15, akg = lane >> 4;
    f32x4 acc0[13];
#pragma unroll
    for (int nt = 0; nt < 13; ++nt) acc0[nt] = (f32x4){0.f, 0.f, 0.f, 0.f};

    for (int c = 0; c < 5; ++c) {
        // stage comb chunk c: cols c*128..c*128+127 for rows b0..b0+15
        for (int idx = lane; idx < 1024; idx += 64) {
            int row = idx >> 6, c2 = (idx & 63) * 2;
            int g = (b0 + row) * 128 + c2;
            float2 v;
            if (c == 0) v = *(const float2*)&user[g];
            else if (c == 1) v = *(const float2*)&item[g];
            else if (c == 2) v = *(const float2*)&hsum[g];
            else if (c == 3) { float2 a = *(const float2*)&item[g]; float2 h = *(const float2*)&hsum[g];
                               v.x = a.x * h.x; v.y = a.y * h.y; }
            else v = *(const float2*)&attf[g];
            unsigned pv = (unsigned)(unsigned short)f2bf(v.x) | ((unsigned)(unsigned short)f2bf(v.y) << 16);
            *(unsigned*)((char*)xb + row * 256 + ((c2 * 2) ^ ((row & 7) << 4))) = pv;
        }
        __syncthreads();
        bf16x8 af[4];
#pragma unroll
        for (int kt = 0; kt < 4; ++kt)
            af[kt] = *(const bf16x8*)((const char*)xb + arow * 256 + ((kt * 64 + akg * 16) ^ ((arow & 7) << 4)));
#pragma unroll
        for (int nt = 0; nt < 13; ++nt) {
#pragma unroll
            for (int kt = 0; kt < 4; ++kt) {
                int ktg = c * 4 + kt;
                bf16x8 bf = ((const bf16x8*)W0h)[(nt * 20 + ktg) * 64 + lane];
                acc0[nt] = __builtin_amdgcn_mfma_f32_16x16x32_bf16(af[kt], bf, acc0[nt], 0, 0, 0);
            }
        }
        __syncthreads();
    }

    // sigmoid -> h1b (cols < 200)
#pragma unroll
    for (int nt = 0; nt < 13; ++nt) {
        int col = nt * 16 + arow;
        if (col < 200) {
            float bb = phb0[col];
#pragma unroll
            for (int i = 0; i < 4; ++i) {
                int r2 = akg * 4 + i;
                *(short*)((char*)h1b + r2 * 512 + ((col * 2) ^ ((r2 & 7) << 4))) = f2bf(sigm(acc0[nt][i] + bb));
            }
        }
    }
    __syncthreads();

    // layer2 (200->80 sigmoid) + layer3 (80->1 sigmoid)
    bf16x8 a1[7];
#pragma unroll
    for (int kt = 0; kt < 7; ++kt)
        a1[kt] = *(const bf16x8*)((const char*)h1b + arow * 512 + ((kt * 64 + akg * 16) ^ ((arow & 7) << 4)));
    float pi[4] = {0.f, 0.f, 0.f, 0.f};
#pragma unroll
    for (int nt = 0; nt < 5; ++nt) {
        f32x4 acc = {0.f, 0.f, 0.f, 0.f};
#pragma unroll
        for (int kt = 0; kt < 7; ++kt)
            acc = __builtin_amdgcn_mfma_f32_16x16x32_bf16(a1[kt], ((const bf16x8*)W1h)[(nt * 7 + kt) * 64 + lane], acc, 0, 0, 0);
        int col = nt * 16 + arow;   // 0..79
        float b1 = phb1[col], w2v = phW2[col];
#pragma unroll
        for (int i = 0; i < 4; ++i)
            pi[i] += sigm(acc[i] + b1) * w2v;
    }
#pragma unroll
    for (int off = 1; off < 16; off <<= 1)
#pragma unroll
        for (int i = 0; i < 4; ++i)
            pi[i] += __shfl_xor(pi[i], off);
    if (arow == 0) {
        float b2 = phb2[0];
#pragma unroll
        for (int i = 0; i < 4; ++i)
            out[b0 + akg * 4 + i] = sigm(pi[i] + b2);
    }
}

extern "C" void kernel_launch(void* const* d_in, const int* in_sizes, int n_in,
                              void* d_out, int out_size, void* d_ws, size_t ws_size,
                              hipStream_t stream) {
    const float* user = (const float*)d_in[0];
    const float* hist = (const float*)d_in[1];
    const float* item = (const float*)d_in[2];
    const int* len = (const int*)d_in[4];
    const float* gWih = (const float*)d_in[5];
    const float* gWhh = (const float*)d_in[6];
    const float* gbih = (const float*)d_in[7];
    const float* gbhh = (const float*)d_in[8];
    const float* aWr = (const float*)d_in[9];
    const float* abr = (const float*)d_in[10];
    const float* aWu = (const float*)d_in[11];
    const float* abu = (const float*)d_in[12];
    const float* aWh = (const float*)d_in[13];
    const float* abh = (const float*)d_in[14];
    const float* attW0 = (const float*)d_in[15];
    const float* attb0 = (const float*)d_in[16];
    const float* attW1 = (const float*)d_in[17];
    const float* attb1 = (const float*)d_in[18];
    const float* attW2 = (const float*)d_in[19];
    const float* attb2 = (const float*)d_in[20];
    const float* phW0 = (const float*)d_in[21];
    const float* phb0 = (const float*)d_in[22];
    const float* phW1 = (const float*)d_in[23];
    const float* phb1 = (const float*)d_in[24];
    const float* phW2 = (const float*)d_in[25];
    const float* phb2 = (const float*)d_in[26];

    char* ws = (char*)d_ws;
    size_t off = 0;
    auto alloc = [&](size_t bytes) { char* p = ws + off; off += (bytes + 255) & ~(size_t)255; return p; };
    ushort* keysbf  = (ushort*)alloc((size_t)BB * TT * HH * 2);   // 52.4 MB
    ushort* Weffbf  = (ushort*)alloc((size_t)BB * 10240 * 2);     // 41.9 MB
    float* pooled   = (float*)alloc((size_t)BB * HH * 4);
    float* hsum     = (float*)alloc((size_t)BB * DD * 4);
    float* attf     = (float*)alloc((size_t)BB * HH * 4);
    float* Wk       = (float*)alloc(128 * 80 * 4);
    float* Wd       = (float*)alloc(128 * 80 * 4);
    float* WqmC     = (float*)alloc(128 * 80 * 4);
    float* bias2    = (float*)alloc((size_t)BB * 80 * 4);
    ushort* Pgru    = (ushort*)alloc(98304 * 2);
    ushort* Pa1     = (ushort*)alloc(65536 * 2);
    ushort* Pa2     = (ushort*)alloc(32768 * 2);
    ushort* W1bf    = (ushort*)alloc(4608 * 2);
    ushort* W0h     = (ushort*)alloc(133120 * 2);
    ushort* W1h     = (ushort*)alloc(17920 * 2);
    (void)in_sizes; (void)n_in; (void)out_size; (void)ws_size;

    k_prep<<<40, 256, 0, stream>>>(attW0, Wk, Wd, WqmC);
    k_pack<<<520, 256, 0, stream>>>(gWih, gWhh, aWr, aWu, aWh, attW1, phW0, phW1,
                                    Pgru, Pa1, Pa2, W1bf, W0h, W1h);
    k_weffbf<<<BB, 256, 0, stream>>>(item, Wk, Wd, WqmC, attb0, Weffbf, bias2);
    k_gru_mfma<<<256, 512, 0, stream>>>(hist, Pgru, gbih, gbhh, len, keysbf, hsum);
    k_attnsoft<<<BB, 512, 0, stream>>>(keysbf, Weffbf, bias2, W1bf, attb1, attW2, attb2, len, pooled);
    k_augru_mfma<<<256, 512, 0, stream>>>(keysbf, pooled, len, Pa1, Pa2, abr, abu, abh, attf);
    k_head<<<128, 64, 0, stream>>>(user, item, hsum, attf, W0h, W1h, phb0, phb1, phW2, phb2, (float*)d_out);
}

// Round 6
// 410.175 us; speedup vs baseline: 11.9209x; 1.3175x over previous
//
#include <hip/hip_runtime.h>
#include <math.h>

#define BB 2048
#define TT 100
#define DD 128
#define HH 128

typedef __attribute__((ext_vector_type(8))) short bf16x8;
typedef __attribute__((ext_vector_type(4))) float f32x4;

__device__ __forceinline__ float sigm(float x) {
    return __builtin_amdgcn_rcpf(1.f + __expf(-x));
}
__device__ __forceinline__ float tanh_fast(float x) {
    x = fminf(fmaxf(x, -15.f), 15.f);
    float e = __expf(2.f * x);
    return (e - 1.f) * __builtin_amdgcn_rcpf(e + 1.f);
}
__device__ __forceinline__ short f2bf(float f) {
    union { float f; unsigned u; } v; v.f = f;
    unsigned r = v.u + 0x7FFF + ((v.u >> 16) & 1);
    return (short)(r >> 16);
}
__device__ __forceinline__ float bf2f(ushort u) {
    union { unsigned u; float f; } v; v.u = ((unsigned)u) << 16;
    return v.f;
}

// A-fragment LDS access (row-swizzled, 256B row stride)
#define RD_A(buf, kk) (*(const bf16x8*)((const char*)(buf) + arow * 256 + (((kk) * 64 + akg * 16) ^ ((arow & 7) << 4))))
#define ST_A(buf, row, c, val) (*(short*)((char*)(buf) + (row) * 256 + (((c) * 2) ^ (((row) & 7) << 4))) = (val))

// ---------------- prep: attention layer0 factorization ----------------
__global__ void k_prep(const float* __restrict__ attW0,
                       float* __restrict__ Wk, float* __restrict__ Wd, float* __restrict__ WqmC) {
    int i = blockIdx.x * 256 + threadIdx.x;
    if (i < 128 * 80) {
        int d = i / 80, j = i - d * 80;
        Wk[i]   = attW0[j * 512 + d] + attW0[j * 512 + 256 + d];
        Wd[i]   = attW0[j * 512 + 384 + d];
        WqmC[i] = attW0[j * 512 + 128 + d] - attW0[j * 512 + 256 + d];
    }
}

// ---------------- pack weights into MFMA B-fragment order (bf16) ----------------
__global__ void k_pack(const float* __restrict__ Wih, const float* __restrict__ Whh,
                       const float* __restrict__ Wr, const float* __restrict__ Wu, const float* __restrict__ Wh,
                       const float* __restrict__ attW1,
                       const float* __restrict__ phW0, const float* __restrict__ phW1,
                       ushort* __restrict__ Pgru, ushort* __restrict__ Pa1, ushort* __restrict__ Pa2,
                       ushort* __restrict__ W1bf, ushort* __restrict__ W0h, ushort* __restrict__ W1h) {
    int n = blockIdx.x * 256 + threadIdx.x;
    if (n < 98304) { // GRU: 48 tiles (0..23 Wih cols, 24..47 Whh cols), 4 k-tiles
        int tile = n >> 11, kt = (n >> 9) & 3, li = (n >> 3) & 63, e = n & 7;
        int k = kt * 32 + (li >> 4) * 8 + e;
        float s;
        if (tile < 24) { int j = tile * 16 + (li & 15); s = Wih[j * 128 + k]; }
        else           { int j = (tile - 24) * 16 + (li & 15); s = Whh[j * 128 + k]; }
        Pgru[n] = (ushort)f2bf(s);
    }
    if (n < 65536) { // AUGRU P1: 16 tiles (cols: 0..127 r, 128..255 u), 8 k-tiles
        int tile = n >> 12, kt = (n >> 9) & 7, li = (n >> 3) & 63, e = n & 7;
        int k = kt * 32 + (li >> 4) * 8 + e;
        int jj = tile * 16 + (li & 15);
        float s = (jj < 128) ? Wr[jj * 256 + k] : Wu[(jj - 128) * 256 + k];
        Pa1[n] = (ushort)f2bf(s);
    }
    if (n < 32768) { // AUGRU P2: 8 tiles (Wh cols), 8 k-tiles
        int tile = n >> 12, kt = (n >> 9) & 7, li = (n >> 3) & 63, e = n & 7;
        int k = kt * 32 + (li >> 4) * 8 + e;
        int j = tile * 16 + (li & 15);
        Pa2[n] = (ushort)f2bf(Wh[j * 256 + k]);
    }
    if (n < 4608) { // attention layer1: 3 nt x 3 kt (K=80->96, N=40->48)
        int g = n >> 9;
        int nt = g / 3, kt = g - nt * 3;
        int li = (n >> 3) & 63, e = n & 7;
        int k = kt * 32 + (li >> 4) * 8 + e;
        int j2 = nt * 16 + (li & 15);
        float s = (k < 80 && j2 < 40) ? attW1[j2 * 80 + k] : 0.f;
        W1bf[n] = (ushort)f2bf(s);
    }
    if (n < 133120) { // predict-head layer0: 13 nt x 20 kt (N=200->208, K=640)
        int g = n >> 9;
        int nt = g / 20, kt = g - nt * 20;
        int li = (n >> 3) & 63, e = n & 7;
        int k = kt * 32 + (li >> 4) * 8 + e;
        int j = nt * 16 + (li & 15);
        W0h[n] = (ushort)f2bf((j < 200) ? phW0[j * 640 + k] : 0.f);
    }
    if (n < 17920) { // predict-head layer1: 5 nt x 7 kt (N=80, K=200->224)
        int g = n >> 9;
        int nt = g / 7, kt = g - nt * 7;
        int li = (n >> 3) & 63, e = n & 7;
        int k = kt * 32 + (li >> 4) * 8 + e;
        int j = nt * 16 + (li & 15);
        W1h[n] = (ushort)f2bf((k < 200 && j < 80) ? phW1[j * 200 + k] : 0.f);
    }
}

// ---------------- per-b effective layer0 weights, bf16 fragment order ----------------
__global__ void k_weffbf(const float* __restrict__ item, const float* __restrict__ Wk,
                         const float* __restrict__ Wd, const float* __restrict__ WqmC,
                         const float* __restrict__ attb0,
                         ushort* __restrict__ Weffbf, float* __restrict__ bias2) {
    int b = blockIdx.x, tid = threadIdx.x;
    __shared__ float q[128];
    if (tid < 128) q[tid] = item[b * 128 + tid];
    __syncthreads();
    ushort* Wb = Weffbf + (size_t)b * 10240;
    for (int idx = tid; idx < 10240; idx += 256) {
        int e = idx & 7, li = (idx >> 3) & 63, kt = (idx >> 9) & 3, nt = idx >> 11;
        int d = kt * 32 + (li >> 4) * 8 + e;
        int j = nt * 16 + (li & 15);
        Wb[idx] = (ushort)f2bf(Wk[d * 80 + j] + q[d] * Wd[d * 80 + j]);
    }
    if (tid < 80) {
        float s = attb0[tid];
        for (int d = 0; d < 128; ++d) s += q[d] * WqmC[d * 80 + tid];
        bias2[b * 80 + tid] = s;
    }
}

// ---------------- GRU scan via MFMA, in-register gates ----------------
// 256 blocks x 512 thr (8 waves), 8 batch rows (M pad 16).
// Wave w owns gate cols c = 16w+(lane&15): Gi tiles {w,8+w,16+w} (A=x), Gh tiles {24+w,...} (A=h).
// r/z gates: x+h parts accumulate into ONE acc. h state in C-layout registers.
__global__ __launch_bounds__(512) void k_gru_mfma(const float* __restrict__ hist,
                                                  const ushort* __restrict__ Wp,
                                                  const float* __restrict__ bih, const float* __restrict__ bhh,
                                                  const int* __restrict__ len,
                                                  ushort* __restrict__ keysbf, float* __restrict__ hsum) {
    int tid = threadIdx.x;
    int lane = tid & 63, w = tid >> 6;
    int b0 = blockIdx.x * 8;

    __shared__ ushort xbf[16 * 128];
    __shared__ ushort hbf[2][16 * 128];   // double-buffered A-layout h
    __shared__ int    ln_s[8];

    for (int e = tid; e < 16 * 128; e += 512) { xbf[e] = 0; hbf[0][e] = 0; hbf[1][e] = 0; }
    if (tid < 8) ln_s[tid] = len[b0 + tid];

    const bf16x8* Wv = (const bf16x8*)Wp;
    bf16x8 bfx[3][4], bfh[3][4];
#pragma unroll
    for (int g = 0; g < 3; ++g)
#pragma unroll
        for (int kt = 0; kt < 4; ++kt) {
            bfx[g][kt] = Wv[((g * 8 + w) * 4 + kt) * 64 + lane];
            bfh[g][kt] = Wv[(((24 + g * 8 + w)) * 4 + kt) * 64 + lane];
        }

    int arow = lane & 15, akg = lane >> 4;
    int c = w * 16 + arow;
    float birq = bih[c] + bhh[c];
    float bizq = bih[128 + c] + bhh[128 + c];
    float bin  = bih[256 + c];
    float bqn  = bhh[256 + c];
    float hold[4] = {0.f, 0.f, 0.f, 0.f};

    __syncthreads();

    int srow = tid >> 6, sd0 = (tid & 63) * 2;
    int Lrow = ln_s[srow];
    const float* hsrc = &hist[(size_t)(b0 + srow) * TT * DD + sd0];
    float2 v = *(const float2*)hsrc;       // x(0)
    float sum0 = 0.f, sum1 = 0.f;
    int p = 0;

    for (int t = 0; t < TT; ++t) {
        // stage x_t, prefetch x_{t+1}
        {
            unsigned pv = (unsigned)(unsigned short)f2bf(v.x) | ((unsigned)(unsigned short)f2bf(v.y) << 16);
            *(unsigned*)((char*)xbf + srow * 256 + ((sd0 * 2) ^ ((srow & 7) << 4))) = pv;
            if (t < Lrow) { sum0 += v.x; sum1 += v.y; }
            if (t + 1 < TT) v = *(const float2*)(hsrc + (size_t)(t + 1) * DD);
        }
        __syncthreads();

        const ushort* hb = hbf[p];
        bf16x8 ax[4], ah[4];
#pragma unroll
        for (int kt = 0; kt < 4; ++kt) { ax[kt] = RD_A(xbf, kt); ah[kt] = RD_A(hb, kt); }

        f32x4 accr = {0.f,0.f,0.f,0.f}, accz = {0.f,0.f,0.f,0.f};
        f32x4 accnx = {0.f,0.f,0.f,0.f}, accnh = {0.f,0.f,0.f,0.f};
#pragma unroll
        for (int kt = 0; kt < 4; ++kt) {
            accr  = __builtin_amdgcn_mfma_f32_16x16x32_bf16(ax[kt], bfx[0][kt], accr, 0, 0, 0);
            accr  = __builtin_amdgcn_mfma_f32_16x16x32_bf16(ah[kt], bfh[0][kt], accr, 0, 0, 0);
            accz  = __builtin_amdgcn_mfma_f32_16x16x32_bf16(ax[kt], bfx[1][kt], accz, 0, 0, 0);
            accz  = __builtin_amdgcn_mfma_f32_16x16x32_bf16(ah[kt], bfh[1][kt], accz, 0, 0, 0);
            accnx = __builtin_amdgcn_mfma_f32_16x16x32_bf16(ax[kt], bfx[2][kt], accnx, 0, 0, 0);
            accnh = __builtin_amdgcn_mfma_f32_16x16x32_bf16(ah[kt], bfh[2][kt], accnh, 0, 0, 0);
        }

        ushort* hbw = (ushort*)hbf[p ^ 1];
#pragma unroll
        for (int i = 0; i < 4; ++i) {
            float r = sigm(accr[i] + birq);
            float z = sigm(accz[i] + bizq);
            float nn = tanh_fast(accnx[i] + bin + r * (accnh[i] + bqn));
            float hnew = (1.f - z) * nn + z * hold[i];
            hold[i] = hnew;
            if (akg < 2) {
                int row = akg * 4 + i;
                short hb16 = f2bf(hnew);
                ST_A(hbw, row, c, hb16);
                keysbf[((size_t)(b0 + row) * TT + t) * HH + c] = (ushort)hb16;
            }
        }
        p ^= 1;
        __syncthreads();
    }

    hsum[(b0 + srow) * 128 + sd0]     = sum0 / (float)Lrow;
    hsum[(b0 + srow) * 128 + sd0 + 1] = sum1 / (float)Lrow;
}

// ---------------- fused attention MLP + masked softmax + pooled (one block per b) ----------------
__global__ __launch_bounds__(512) void k_attnsoft(const ushort* __restrict__ keysbf,
                                                  const ushort* __restrict__ Weffbf,
                                                  const float* __restrict__ bias2,
                                                  const ushort* __restrict__ W1bf,
                                                  const float* __restrict__ attb1, const float* __restrict__ attW2,
                                                  const float* __restrict__ attb2,
                                                  const int* __restrict__ len,
                                                  float* __restrict__ pooled) {
    int tid = threadIdx.x;
    int lane = tid & 63, w = tid >> 6;
    int b = blockIdx.x;

    __shared__ ushort kbf[112 * 128];
    __shared__ ushort scbf[112 * 96];
    __shared__ float  bias2s[80];
    __shared__ float  b1s[48];
    __shared__ float  W2s[48];
    __shared__ float  attn_s[128];
    __shared__ float  red[128];

    bf16x8 bfrag0[5][4];
    bf16x8 bfrag1[3][3];
    if (w < 7) {
        const bf16x8* Wb = (const bf16x8*)(Weffbf + (size_t)b * 10240);
#pragma unroll
        for (int nt = 0; nt < 5; ++nt)
#pragma unroll
            for (int kt = 0; kt < 4; ++kt)
                bfrag0[nt][kt] = Wb[(nt * 4 + kt) * 64 + lane];
#pragma unroll
        for (int nt = 0; nt < 3; ++nt)
#pragma unroll
            for (int kt = 0; kt < 3; ++kt)
                bfrag1[nt][kt] = ((const bf16x8*)W1bf)[(nt * 3 + kt) * 64 + lane];
    }

    const ushort* ksrc = keysbf + (size_t)b * TT * 128;
    for (int e = tid; e < 3584; e += 512) {
        int row = e >> 5, c4 = e & 31;
        uint2 pv;
        if (row < TT) pv = *(const uint2*)(ksrc + row * 128 + c4 * 4);
        else { pv.x = 0; pv.y = 0; }
        *(uint2*)((char*)kbf + row * 256 + ((c4 * 8) ^ ((row & 7) << 4))) = pv;
    }
    for (int e = tid; e < 1792; e += 512) {
        int row = e >> 4, c = 80 + (e & 15);
        *(ushort*)((char*)scbf + row * 192 + ((c * 2) ^ ((row & 7) << 4))) = 0;
    }
    if (tid < 80) bias2s[tid] = bias2[b * 80 + tid];
    if (tid < 48) {
        b1s[tid] = (tid < 40) ? attb1[tid] : 0.f;
        W2s[tid] = (tid < 40) ? attW2[tid] : 0.f;
    }
    __syncthreads();

    if (w < 7) {
        int arow = lane & 15, akg = lane >> 4;
        int row = w * 16 + arow;
        bf16x8 af[4];
#pragma unroll
        for (int kt = 0; kt < 4; ++kt)
            af[kt] = *(const bf16x8*)((const char*)kbf + row * 256 + (((kt * 64 + akg * 16)) ^ ((row & 7) << 4)));
#pragma unroll
        for (int nt = 0; nt < 5; ++nt) {
            f32x4 acc = {0.f, 0.f, 0.f, 0.f};
#pragma unroll
            for (int kt = 0; kt < 4; ++kt)
                acc = __builtin_amdgcn_mfma_f32_16x16x32_bf16(af[kt], bfrag0[nt][kt], acc, 0, 0, 0);
            int col = nt * 16 + arow;
            float bcol = bias2s[col];
#pragma unroll
            for (int i = 0; i < 4; ++i) {
                int r2 = w * 16 + akg * 4 + i;
                float vsc = fmaxf(acc[i] + bcol, 0.f);
                *(short*)((char*)scbf + r2 * 192 + ((col * 2) ^ ((r2 & 7) << 4))) = f2bf(vsc);
            }
        }
    }
    __syncthreads();

    if (w < 7) {
        int arow = lane & 15, akg = lane >> 4;
        int row = w * 16 + arow;
        bf16x8 a1[3];
#pragma unroll
        for (int kt = 0; kt < 3; ++kt)
            a1[kt] = *(const bf16x8*)((const char*)scbf + row * 192 + (((kt * 64 + akg * 16)) ^ ((row & 7) << 4)));
        float pi[4] = {0.f, 0.f, 0.f, 0.f};
#pragma unroll
        for (int nt = 0; nt < 3; ++nt) {
            f32x4 acc = {0.f, 0.f, 0.f, 0.f};
#pragma unroll
            for (int kt = 0; kt < 3; ++kt)
                acc = __builtin_amdgcn_mfma_f32_16x16x32_bf16(a1[kt], bfrag1[nt][kt], acc, 0, 0, 0);
            int col = nt * 16 + arow;
            float wb = W2s[col], bb1 = b1s[col];
#pragma unroll
            for (int i = 0; i < 4; ++i)
                pi[i] += fmaxf(acc[i] + bb1, 0.f) * wb;
        }
#pragma unroll
        for (int off = 1; off < 16; off <<= 1)
#pragma unroll
            for (int i = 0; i < 4; ++i)
                pi[i] += __shfl_xor(pi[i], off);
        if ((lane & 15) == 0) {
            float b2 = attb2[0];
#pragma unroll
            for (int i = 0; i < 4; ++i) {
                int t = w * 16 + akg * 4 + i;
                if (t < 128) attn_s[t] = fmaxf(pi[i] + b2, 0.f);
            }
        }
    }
    __syncthreads();

    int L = len[b];
    if (tid < 128) red[tid] = (tid < L) ? attn_s[tid] : -INFINITY;
    __syncthreads();
    for (int o = 64; o >= 1; o >>= 1) { if (tid < o) red[tid] = fmaxf(red[tid], red[tid + o]); __syncthreads(); }
    float mx = red[0];
    __syncthreads();
    if (tid < 128) {
        float e = (tid < L) ? __expf(attn_s[tid] - mx) : 0.f;
        attn_s[tid] = e; red[tid] = e;
    }
    __syncthreads();
    for (int o = 64; o >= 1; o >>= 1) { if (tid < o) red[tid] += red[tid + o]; __syncthreads(); }
    float inv = __builtin_amdgcn_rcpf(red[0]);
    if (tid < 128) {
        int d = tid;
        float p = 0.f;
        for (int t2 = 0; t2 < L; ++t2) {
            ushort kv = *(const ushort*)((const char*)kbf + t2 * 256 + ((d * 2) ^ ((t2 & 7) << 4)));
            p += attn_s[t2] * bf2f(kv);
        }
        pooled[b * 128 + d] = p * inv;
    }
}

// ---------------- AUGRU scan via MFMA, in-register gates ----------------
// Wave w owns cols c=16w+(lane&15): P1 r-tile w + u-tile 8+w; P2 Wh-tile w. 2 barriers/step.
__global__ __launch_bounds__(512) void k_augru_mfma(const ushort* __restrict__ keysbf,
                                                    const float* __restrict__ pooled,
                                                    const int* __restrict__ len,
                                                    const ushort* __restrict__ Wp1, const ushort* __restrict__ Wp2,
                                                    const float* __restrict__ br, const float* __restrict__ bu,
                                                    const float* __restrict__ bh,
                                                    float* __restrict__ att_feat) {
    int tid = threadIdx.x;
    int lane = tid & 63, w = tid >> 6;
    int b0 = blockIdx.x * 8;

    __shared__ ushort hbf[16 * 128], xbf[16 * 128], rhbf[16 * 128];
    __shared__ float as_[16];
    __shared__ int ln_s[8];

    for (int e = tid; e < 16 * 128; e += 512) { hbf[e] = 0; xbf[e] = 0; rhbf[e] = 0; }
    if (tid < 16) as_[tid] = 0.f;
    if (tid < 8) ln_s[tid] = len[b0 + tid];

    const bf16x8* W1v = (const bf16x8*)Wp1;
    const bf16x8* W2v = (const bf16x8*)Wp2;
    bf16x8 b1r[8], b1u[8], b2[8];
#pragma unroll
    for (int kt = 0; kt < 8; ++kt) {
        b1r[kt] = W1v[(w * 8 + kt) * 64 + lane];
        b1u[kt] = W1v[((8 + w) * 8 + kt) * 64 + lane];
        b2[kt]  = W2v[(w * 8 + kt) * 64 + lane];
    }

    int arow = lane & 15, akg = lane >> 4;
    int c = w * 16 + arow;
    float brc = br[c], buc = bu[c], bhc = bh[c];
    float hold[4] = {0.f, 0.f, 0.f, 0.f};

    int srow = tid >> 6, sd0 = (tid & 63) * 2;
    const ushort* xsrc = &keysbf[(size_t)(b0 + srow) * TT * HH + sd0];
    // prologue: stage x(0), a(0); prefetch x(1), a(1)
    unsigned v0 = *(const unsigned*)xsrc;
    __syncthreads();  // cover zero-init before first writes
    *(unsigned*)((char*)xbf + srow * 256 + ((sd0 * 2) ^ ((srow & 7) << 4))) = v0;
    unsigned vnext = (TT > 1) ? *(const unsigned*)(xsrc + (size_t)1 * HH) : 0u;
    float areg = 0.f;
    if (tid < 8) {
        as_[tid] = pooled[(b0 + tid) * HH + 0];
        if (TT > 1) areg = pooled[(b0 + tid) * HH + 1];
    }
    __syncthreads();

    for (int t = 0; t < TT; ++t) {
        // ---- P1 ----
        bf16x8 ah[4], ax[4];
#pragma unroll
        for (int kt = 0; kt < 4; ++kt) { ah[kt] = RD_A(hbf, kt); ax[kt] = RD_A(xbf, kt); }
        f32x4 accr = {0.f,0.f,0.f,0.f}, accu = {0.f,0.f,0.f,0.f};
#pragma unroll
        for (int kt = 0; kt < 4; ++kt) {
            accr = __builtin_amdgcn_mfma_f32_16x16x32_bf16(ah[kt], b1r[kt], accr, 0, 0, 0);
            accr = __builtin_amdgcn_mfma_f32_16x16x32_bf16(ax[kt], b1r[4 + kt], accr, 0, 0, 0);
            accu = __builtin_amdgcn_mfma_f32_16x16x32_bf16(ah[kt], b1u[kt], accu, 0, 0, 0);
            accu = __builtin_amdgcn_mfma_f32_16x16x32_bf16(ax[kt], b1u[4 + kt], accu, 0, 0, 0);
        }
        float u_reg[4];
#pragma unroll
        for (int i = 0; i < 4; ++i) {
            float r = sigm(accr[i] + brc);
            float a = as_[akg * 4 + i];
            u_reg[i] = a * sigm(accu[i] + buc);
            if (akg < 2) ST_A(rhbf, akg * 4 + i, c, f2bf(r * hold[i]));
        }
        __syncthreads();

        // ---- P2 ----
        bf16x8 arh[4];
#pragma unroll
        for (int kt = 0; kt < 4; ++kt) arh[kt] = RD_A(rhbf, kt);
        f32x4 acch = {0.f,0.f,0.f,0.f};
#pragma unroll
        for (int kt = 0; kt < 4; ++kt) {
            acch = __builtin_amdgcn_mfma_f32_16x16x32_bf16(arh[kt], b2[kt], acch, 0, 0, 0);
            acch = __builtin_amdgcn_mfma_f32_16x16x32_bf16(ax[kt], b2[4 + kt], acch, 0, 0, 0);
        }
#pragma unroll
        for (int i = 0; i < 4; ++i) {
            float hhat = tanh_fast(acch[i] + bhc);
            float hnew = (1.f - u_reg[i]) * hold[i] + u_reg[i] * hhat;
            hold[i] = hnew;
            if (akg < 2) {
                int row = akg * 4 + i;
                ST_A(hbf, row, c, f2bf(hnew));
                if (t == ln_s[row] - 1) att_feat[(b0 + row) * HH + c] = hnew;
            }
        }
        // stage x(t+1), a(t+1); prefetch t+2
        if (t + 1 < TT) {
            *(unsigned*)((char*)xbf + srow * 256 + ((sd0 * 2) ^ ((srow & 7) << 4))) = vnext;
            if (tid < 8) as_[tid] = areg;
            if (t + 2 < TT) {
                vnext = *(const unsigned*)(xsrc + (size_t)(t + 2) * HH);
                if (tid < 8) areg = pooled[(b0 + tid) * HH + t + 2];
            }
        }
        __syncthreads();
    }
}

// ---------------- fused predict head: comb -> 200 -> 80 -> 1, all sigmoid ----------------
__global__ __launch_bounds__(64) void k_head(const float* __restrict__ user, const float* __restrict__ item,
                                             const float* __restrict__ hsum, const float* __restrict__ attf,
                                             const ushort* __restrict__ W0h, const ushort* __restrict__ W1h,
                                             const float* __restrict__ phb0, const float* __restrict__ phb1,
                                             const float* __restrict__ phW2, const float* __restrict__ phb2,
                                             float* __restrict__ out) {
    int lane = threadIdx.x;
    int b0 = blockIdx.x * 16;
    __shared__ ushort xb[16 * 128];
    __shared__ ushort h1b[16 * 256];

    for (int e = lane; e < 4096; e += 64) h1b[e] = 0;

    int arow = lane & 15, akg = lane >> 4;
    f32x4 acc0[13];
#pragma unroll
    for (int nt = 0; nt < 13; ++nt) acc0[nt] = (f32x4){0.f, 0.f, 0.f, 0.f};

    for (int c = 0; c < 5; ++c) {
        for (int idx = lane; idx < 1024; idx += 64) {
            int row = idx >> 6, c2 = (idx & 63) * 2;
            int g = (b0 + row) * 128 + c2;
            float2 v;
            if (c == 0) v = *(const float2*)&user[g];
            else if (c == 1) v = *(const float2*)&item[g];
            else if (c == 2) v = *(const float2*)&hsum[g];
            else if (c == 3) { float2 a = *(const float2*)&item[g]; float2 h = *(const float2*)&hsum[g];
                               v.x = a.x * h.x; v.y = a.y * h.y; }
            else v = *(const float2*)&attf[g];
            unsigned pv = (unsigned)(unsigned short)f2bf(v.x) | ((unsigned)(unsigned short)f2bf(v.y) << 16);
            *(unsigned*)((char*)xb + row * 256 + ((c2 * 2) ^ ((row & 7) << 4))) = pv;
        }
        __syncthreads();
        bf16x8 af[4];
#pragma unroll
        for (int kt = 0; kt < 4; ++kt)
            af[kt] = *(const bf16x8*)((const char*)xb + arow * 256 + ((kt * 64 + akg * 16) ^ ((arow & 7) << 4)));
#pragma unroll
        for (int nt = 0; nt < 13; ++nt) {
#pragma unroll
            for (int kt = 0; kt < 4; ++kt) {
                int ktg = c * 4 + kt;
                bf16x8 bf = ((const bf16x8*)W0h)[(nt * 20 + ktg) * 64 + lane];
                acc0[nt] = __builtin_amdgcn_mfma_f32_16x16x32_bf16(af[kt], bf, acc0[nt], 0, 0, 0);
            }
        }
        __syncthreads();
    }

#pragma unroll
    for (int nt = 0; nt < 13; ++nt) {
        int col = nt * 16 + arow;
        if (col < 200) {
            float bb = phb0[col];
#pragma unroll
            for (int i = 0; i < 4; ++i) {
                int r2 = akg * 4 + i;
                *(short*)((char*)h1b + r2 * 512 + ((col * 2) ^ ((r2 & 7) << 4))) = f2bf(sigm(acc0[nt][i] + bb));
            }
        }
    }
    __syncthreads();

    bf16x8 a1[7];
#pragma unroll
    for (int kt = 0; kt < 7; ++kt)
        a1[kt] = *(const bf16x8*)((const char*)h1b + arow * 512 + ((kt * 64 + akg * 16) ^ ((arow & 7) << 4)));
    float pi[4] = {0.f, 0.f, 0.f, 0.f};
#pragma unroll
    for (int nt = 0; nt < 5; ++nt) {
        f32x4 acc = {0.f, 0.f, 0.f, 0.f};
#pragma unroll
        for (int kt = 0; kt < 7; ++kt)
            acc = __builtin_amdgcn_mfma_f32_16x16x32_bf16(a1[kt], ((const bf16x8*)W1h)[(nt * 7 + kt) * 64 + lane], acc, 0, 0, 0);
        int col = nt * 16 + arow;
        float b1 = phb1[col], w2v = phW2[col];
#pragma unroll
        for (int i = 0; i < 4; ++i)
            pi[i] += sigm(acc[i] + b1) * w2v;
    }
#pragma unroll
    for (int off = 1; off < 16; off <<= 1)
#pragma unroll
        for (int i = 0; i < 4; ++i)
            pi[i] += __shfl_xor(pi[i], off);
    if (arow == 0) {
        float b2 = phb2[0];
#pragma unroll
        for (int i = 0; i < 4; ++i)
            out[b0 + akg * 4 + i] = sigm(pi[i] + b2);
    }
}

extern "C" void kernel_launch(void* const* d_in, const int* in_sizes, int n_in,
                              void* d_out, int out_size, void* d_ws, size_t ws_size,
                              hipStream_t stream) {
    const float* user = (const float*)d_in[0];
    const float* hist = (const float*)d_in[1];
    const float* item = (const float*)d_in[2];
    const int* len = (const int*)d_in[4];
    const float* gWih = (const float*)d_in[5];
    const float* gWhh = (const float*)d_in[6];
    const float* gbih = (const float*)d_in[7];
    const float* gbhh = (const float*)d_in[8];
    const float* aWr = (const float*)d_in[9];
    const float* abr = (const float*)d_in[10];
    const float* aWu = (const float*)d_in[11];
    const float* abu = (const float*)d_in[12];
    const float* aWh = (const float*)d_in[13];
    const float* abh = (const float*)d_in[14];
    const float* attW0 = (const float*)d_in[15];
    const float* attb0 = (const float*)d_in[16];
    const float* attW1 = (const float*)d_in[17];
    const float* attb1 = (const float*)d_in[18];
    const float* attW2 = (const float*)d_in[19];
    const float* attb2 = (const float*)d_in[20];
    const float* phW0 = (const float*)d_in[21];
    const float* phb0 = (const float*)d_in[22];
    const float* phW1 = (const float*)d_in[23];
    const float* phb1 = (const float*)d_in[24];
    const float* phW2 = (const float*)d_in[25];
    const float* phb2 = (const float*)d_in[26];

    char* ws = (char*)d_ws;
    size_t off = 0;
    auto alloc = [&](size_t bytes) { char* p = ws + off; off += (bytes + 255) & ~(size_t)255; return p; };
    ushort* keysbf  = (ushort*)alloc((size_t)BB * TT * HH * 2);
    ushort* Weffbf  = (ushort*)alloc((size_t)BB * 10240 * 2);
    float* pooled   = (float*)alloc((size_t)BB * HH * 4);
    float* hsum     = (float*)alloc((size_t)BB * DD * 4);
    float* attf     = (float*)alloc((size_t)BB * HH * 4);
    float* Wk       = (float*)alloc(128 * 80 * 4);
    float* Wd       = (float*)alloc(128 * 80 * 4);
    float* WqmC     = (float*)alloc(128 * 80 * 4);
    float* bias2    = (float*)alloc((size_t)BB * 80 * 4);
    ushort* Pgru    = (ushort*)alloc(98304 * 2);
    ushort* Pa1     = (ushort*)alloc(65536 * 2);
    ushort* Pa2     = (ushort*)alloc(32768 * 2);
    ushort* W1bf    = (ushort*)alloc(4608 * 2);
    ushort* W0h     = (ushort*)alloc(133120 * 2);
    ushort* W1h     = (ushort*)alloc(17920 * 2);
    (void)in_sizes; (void)n_in; (void)out_size; (void)ws_size;

    k_prep<<<40, 256, 0, stream>>>(attW0, Wk, Wd, WqmC);
    k_pack<<<520, 256, 0, stream>>>(gWih, gWhh, aWr, aWu, aWh, attW1, phW0, phW1,
                                    Pgru, Pa1, Pa2, W1bf, W0h, W1h);
    k_weffbf<<<BB, 256, 0, stream>>>(item, Wk, Wd, WqmC, attb0, Weffbf, bias2);
    k_gru_mfma<<<256, 512, 0, stream>>>(hist, Pgru, gbih, gbhh, len, keysbf, hsum);
    k_attnsoft<<<BB, 512, 0, stream>>>(keysbf, Weffbf, bias2, W1bf, attb1, attW2, attb2, len, pooled);
    k_augru_mfma<<<256, 512, 0, stream>>>(keysbf, pooled, len, Pa1, Pa2, abr, abu, abh, attf);
    k_head<<<128, 64, 0, stream>>>(user, item, hsum, attf, W0h, W1h, phb0, phb1, phW2, phb2, (float*)d_out);
}